// Round 9
// baseline (236.717 us; speedup 1.0000x reference)
//
#include <hip/hip_runtime.h>
#include <hip/hip_bf16.h>
#include <math.h>

typedef short s16x8 __attribute__((ext_vector_type(8)));
typedef float f32x4 __attribute__((ext_vector_type(4)));

__device__ inline ushort f2bf(float f) {
  unsigned u = __float_as_uint(f);
  u = (u + 0x7FFF + ((u >> 16) & 1)) >> 16;
  return (ushort)u;
}
__device__ inline float bf2f(ushort u) {
  return __uint_as_float(((unsigned)u) << 16);
}
// packed f32x2 -> bf16x2 RNE (bit-identical to f2bf pair)
__device__ inline unsigned pkbf(float a, float b) {
  __hip_bfloat162 h = __float22bfloat162_rn(make_float2(a, b));
  return *(unsigned*)&h;
}
// bf16 pair unpack from a dword (bit-identical to bf2f of lo/hi ushort)
__device__ inline float bflo(unsigned u) { return __uint_as_float(u << 16); }
__device__ inline float bfhi(unsigned u) { return __uint_as_float(u & 0xffff0000u); }
// fast activations: v_exp_f32 + v_rcp_f32; saturate correctly at +/-inf.
__device__ inline float fast_tanh(float v) {
  float e = __builtin_amdgcn_exp2f(v * 2.8853900817779268f);   // exp(2v)
  return 1.f - 2.f * __builtin_amdgcn_rcpf(e + 1.f);
}
__device__ inline float fast_sigmoid(float v) {
  float e = __builtin_amdgcn_exp2f(v * -1.4426950408889634f);  // exp(-v)
  return __builtin_amdgcn_rcpf(1.f + e);
}

// ---- PERMUTED head-row space (640 rows):
//   g in [0,18): off | [18,27): mod | [27,64): pad | [64,640): col j=g-64=k*64+c
//     source col channel cc = c*9+k.
// ---- K1: fused 1x1 conv as MFMA GEMM -> fusedt[pix][64] bf16, xtb (natural order)
//      transpose as a free by-product of B-operand staging, PLUS weight packing
//      (former k_merge) on blocks >= 1024.
// Round-9: float4 wcd loads; ref tile prefetched to regs BEFORE the first barrier
// (HBM latency hides under w_lds + B-x build); pkbf pairs in all bf16 packing.
__global__ __launch_bounds__(256) void k_fused(
    const float* __restrict__ x, const float* __restrict__ ref,
    const float* __restrict__ wcd, const float* __restrict__ bcd,
    const float* __restrict__ wp, const float* __restrict__ bp,
    const float* __restrict__ wm, const float* __restrict__ bm,
    const float* __restrict__ wc, const float* __restrict__ bc,
    const float* __restrict__ wconv,
    ushort* __restrict__ fusedt, ushort* __restrict__ xtb,
    ushort* __restrict__ Wpk, float* __restrict__ Bc, ushort* __restrict__ W2pk) {
  __shared__ float sxf[64][68];                       // 17,408 B (pad 68: b128-aligned)
  __shared__ __align__(16) ushort w_lds[64 * 128];    // 16,384 B  A: [oc][16 chunks]
  __shared__ __align__(16) ushort xt_lds[64 * 128];   // 16,384 B  B: [px][16 chunks]
  __shared__ float sb[64];

  if (blockIdx.x >= 1024) {
    // ---- weight-packing blocks (former k_merge), 1440 blocks ----
    int i = (blockIdx.x - 1024) * 256 + threadIdx.x;
    if (i < 368640) {
      int e = i & 7, lane = (i >> 3) & 63, mi = (i >> 9) & 3, ocq = (i >> 11) & 1;
      int hi = i >> 12;                 // 0..89
      int ks = hi % 18, og = hi / 18;
      int g = og * 128 + ocq * 64 + mi * 16 + (lane & 15);
      int ci = ((ks & 1) << 5) + ((lane >> 4) << 3) + e;
      int kk = ks >> 1;
      int col = ci * 9 + kk;
      float v = 0.f;
      if (g < 18)       v = wp[g * 576 + col];
      else if (g < 27)  v = wm[(g - 18) * 576 + col];
      else if (g >= 64) {
        int j = g - 64;
        int cc = (j & 63) * 9 + (j >> 6);
        v = wc[cc * 576 + col];
      }
      Wpk[i] = f2bf(v);
    }
    if (i < 36864) {
      int e = i & 7, lane = (i >> 3) & 63, mi = (i >> 9) & 3, ks = i >> 11;  // 0..17
      int o = mi * 16 + (lane & 15);
      int p = (ks << 5) + ((lane >> 4) << 3) + e;
      int kk2 = p >> 6, c = p & 63;
      W2pk[i] = f2bf(wconv[o * 576 + c * 9 + kk2]);
    }
    if (i < 640) {
      float bv = 0.f;
      if (i < 18)       bv = bp[i];
      else if (i < 27)  bv = bm[i - 18];
      else if (i >= 64) {
        int j = i - 64;
        bv = bc[(j & 63) * 9 + (j >> 6)];
      }
      Bc[i] = bv;
    }
    return;
  }

  // ---- conv blocks: 64 px each ----
  const int t = threadIdx.x;
  const int b = blockIdx.x >> 8, hw0 = (blockIdx.x & 255) << 6;
  if (t < 64) sb[t] = bcd[t];

  // prefetch ref tile into regs NOW (consumed after B-x build; latency hidden)
  float4 rpre[4];
  #pragma unroll
  for (int rep = 0; rep < 4; rep++) {
    int idx = t + (rep << 8);
    int ci = idx >> 4, p4 = (idx & 15) << 2;
    rpre[rep] = *(const float4*)(ref + ((size_t)((b << 6) + ci) << 14) + hw0 + p4);
  }

  // stage x tile fp32 (coalesced float4)
  #pragma unroll
  for (int rep = 0; rep < 4; rep++) {
    int idx = t + (rep << 8);              // 0..1023 float4s
    int ci = idx >> 4, p4 = (idx & 15) << 2;
    float4 v = *(const float4*)(x + ((size_t)((b << 6) + ci) << 14) + hw0 + p4);
    *(float4*)&sxf[ci][p4] = v;
  }

  // A-operand: w_lds[oc][chunk g slot-rotated], natural K-order; float4 loads.
  #pragma unroll
  for (int rep = 0; rep < 4; rep++) {
    int idx = t + (rep << 8);              // 0..1023 = oc*16 + g
    int oc = idx >> 4, g = idx & 15;
    const float4* wr4 = (const float4*)(wcd + oc * 128 + (g << 3));
    float4 wa = wr4[0], wb2 = wr4[1];
    uint4 ow;
    ow.x = pkbf(wa.x, wa.y);  ow.y = pkbf(wa.z, wa.w);
    ow.z = pkbf(wb2.x, wb2.y); ow.w = pkbf(wb2.z, wb2.w);
    *(uint4*)(w_lds + oc * 128 + (((g + oc) & 15) << 3)) = ow;
  }
  __syncthreads();

  // build B x-half (chunks 0..7, natural); rows == xtb rows -> free global transpose
  #pragma unroll
  for (int rep = 0; rep < 2; rep++) {
    int idx = t + (rep << 8);              // 0..511 = px*8 + g
    int px = idx >> 3, g = idx & 7;
    uint4 ow;
    ow.x = pkbf(sxf[(g << 3) + 0][px], sxf[(g << 3) + 1][px]);
    ow.y = pkbf(sxf[(g << 3) + 2][px], sxf[(g << 3) + 3][px]);
    ow.z = pkbf(sxf[(g << 3) + 4][px], sxf[(g << 3) + 5][px]);
    ow.w = pkbf(sxf[(g << 3) + 6][px], sxf[(g << 3) + 7][px]);
    *(uint4*)(xt_lds + px * 128 + (((g + px) & 15) << 3)) = ow;
    *(uint4*)(xtb + (((size_t)b << 14) + hw0 + px) * 64 + (g << 3)) = ow;
  }
  __syncthreads();   // all sxf(x) reads done before overwrite

  // write prefetched ref tile to sxf (no global wait here)
  #pragma unroll
  for (int rep = 0; rep < 4; rep++) {
    int idx = t + (rep << 8);
    int ci = idx >> 4, p4 = (idx & 15) << 2;
    *(float4*)&sxf[ci][p4] = rpre[rep];
  }
  __syncthreads();

  // build B ref-half (chunks 8..15, natural)
  #pragma unroll
  for (int rep = 0; rep < 2; rep++) {
    int idx = t + (rep << 8);
    int px = idx >> 3, g = (idx & 7) + 8;
    const int e0 = (g & 7) << 3;
    uint4 ow;
    ow.x = pkbf(sxf[e0 + 0][px], sxf[e0 + 1][px]);
    ow.y = pkbf(sxf[e0 + 2][px], sxf[e0 + 3][px]);
    ow.z = pkbf(sxf[e0 + 4][px], sxf[e0 + 5][px]);
    ow.w = pkbf(sxf[e0 + 6][px], sxf[e0 + 7][px]);
    *(uint4*)(xt_lds + px * 128 + (((g + px) & 15) << 3)) = ow;
  }
  __syncthreads();

  // GEMM: wave -> 16 oc, 4 ni x 4 ksteps MFMAs
  const int lane = t & 63, wv4 = t >> 6;
  const int ocl = lane & 15, kb = lane >> 4;
  const int ocr = (wv4 << 4) + ocl;
  f32x4 acc[4];
  #pragma unroll
  for (int ni = 0; ni < 4; ni++) acc[ni] = (f32x4){0.f, 0.f, 0.f, 0.f};
  #pragma unroll
  for (int s = 0; s < 4; s++) {
    const int gA = (s << 2) + kb;
    s16x8 af = *(const s16x8*)(w_lds + ocr * 128 + (((gA + ocr) & 15) << 3));
    #pragma unroll
    for (int ni = 0; ni < 4; ni++) {
      const int px = (ni << 4) + ocl;
      s16x8 bf8 = *(const s16x8*)(xt_lds + px * 128 + (((gA + px) & 15) << 3));
      acc[ni] = __builtin_amdgcn_mfma_f32_16x16x32_bf16(af, bf8, acc[ni], 0, 0, 0);
    }
  }
  // epilogue: +bias, pack bf16, store fusedt[pix][oc]
  const float4 b4 = *(const float4*)&sb[(wv4 << 4) + (kb << 2)];
  #pragma unroll
  for (int ni = 0; ni < 4; ni++) {
    const int px = (ni << 4) + ocl;
    uint2 o;
    o.x = pkbf(acc[ni][0] + b4.x, acc[ni][1] + b4.y);
    o.y = pkbf(acc[ni][2] + b4.z, acc[ni][3] + b4.w);
    *(uint2*)(fusedt + (((size_t)(b << 14) + hw0 + px) << 6) + (wv4 << 4) + (kb << 2)) = o;
  }
}

// ---- K3: FULLY FUSED head-GEMM + sampler + final GEMM, 64-px tiles --------------------
// Round-0/8 structure verbatim (116 us proven regime: small live set, recompute-heavy,
// no prefetch arrays). Round-9 delta: ONLY packed bf16 converts (pkbf/bflo/bfhi) in the
// epilogue + sampler — fewer VALU ops, zero live-state change, bit-identical math.
// grid 1024; block 256 = 4 waves; 4 blocks/CU (LDS 40,448B).
__global__ __launch_bounds__(256) void k_all(
    const ushort* __restrict__ Wpk, const ushort* __restrict__ fusedt,
    const float* __restrict__ Bc, const ushort* __restrict__ xtb,
    const ushort* __restrict__ W2pk, float* __restrict__ out) {
  __shared__ __align__(16) ushort sF[3 * 66 * 64];    // 25,344 B
  __shared__ __align__(16) ushort colT[64 * 64];      //  8,192 B
  __shared__ float homT[64 * 27];                     //  6,912 B
  const int t = threadIdx.x;
  const int lane = t & 63, wv = t >> 6;
  const int rowid = blockIdx.x;           // b*256 + h*2 + half
  const int b = rowid >> 8;
  const int rem = rowid & 255;
  const int h = rem >> 1, hf = rem & 1;
  const int w0 = hf << 6;
  const int hw0 = (h << 7) + w0;

  // stage fused rows h-1..h+1, w1 in [0,66) covering gw in [w0-1, w0+64]
  for (int idx = t; idx < 1584; idx += 256) {   // 198 pixels x 8 ci-chunks
    int p = idx >> 3, j = idx & 7;
    int row = p / 66, w1 = p - row * 66;
    int gh = h + row - 1, gw = w0 + w1 - 1;
    uint4 v = make_uint4(0u, 0u, 0u, 0u);
    if (gh >= 0 && gh < 128 && (unsigned)gw < 128u)
      v = *(const uint4*)(fusedt + ((size_t)((b << 14) + (gh << 7) + gw) << 6) + j * 8);
    int slot = (j + w1) & 7;
    *(uint4*)(sF + (p << 6) + slot * 8) = v;
  }
  __syncthreads();

  const int pxq = wv & 1, rowq = wv >> 1;
  const int nif = lane & 15, kb = lane >> 4, quad = lane >> 4;

  // ---- off/mod GEMM: permuted rows 0..31 (rowq==0 waves only) ----
  if (rowq == 0) {
    f32x4 acc[2][2];
    #pragma unroll
    for (int mi = 0; mi < 2; mi++)
      #pragma unroll
      for (int ni = 0; ni < 2; ni++) acc[mi][ni] = (f32x4){0.f, 0.f, 0.f, 0.f};
    #pragma unroll 2
    for (int ks = 0; ks < 18; ks++) {
      const int kk = ks >> 1, half = ks & 1;
      const int dr = kk / 3, dc = kk - dr * 3;
      const ushort* wp8 = Wpk + ((size_t)(ks << 12)) + (lane << 3);  // og=0, ocq=0
      s16x8 af[2], bfr[2];
      #pragma unroll
      for (int mi = 0; mi < 2; mi++)
        af[mi] = *(const s16x8*)(wp8 + (mi << 9));
      const int gci = half * 4 + kb;
      #pragma unroll
      for (int ni = 0; ni < 2; ni++) {
        int r = (pxq << 5) + ni * 16 + nif;
        int w1 = r + dc;
        int slot = (gci + w1) & 7;
        bfr[ni] = *(const s16x8*)(sF + ((dr * 66 + w1) << 6) + slot * 8);
      }
      #pragma unroll
      for (int mi = 0; mi < 2; mi++)
        #pragma unroll
        for (int ni = 0; ni < 2; ni++)
          acc[mi][ni] = __builtin_amdgcn_mfma_f32_16x16x32_bf16(af[mi], bfr[ni], acc[mi][ni], 0, 0, 0);
    }
    #pragma unroll
    for (int mi = 0; mi < 2; mi++) {
      #pragma unroll
      for (int ni = 0; ni < 2; ni++) {
        int px = (pxq << 5) + ni * 16 + nif;
        #pragma unroll
        for (int r = 0; r < 4; r++) {
          int g = mi * 16 + (quad << 2) + r;
          float v = acc[mi][ni][r] + Bc[g];
          if (g < 18)       homT[px * 27 + g] = v;
          else if (g < 27)  homT[px * 27 + g] = fast_sigmoid(v);
        }
      }
    }
  }

  // sampler per-pixel identity: 4 thr/px x 16 ch
  const int cq = t >> 6, pxl = t & 63, c0 = cq << 4;
  const int ww = w0 + pxl;
  const ushort* xb = xtb + ((size_t)b << 20);

  f32x4 aco[2][2];
  #pragma unroll
  for (int mi = 0; mi < 2; mi++)
    #pragma unroll
    for (int ni = 0; ni < 2; ni++) aco[mi][ni] = (f32x4){0.f, 0.f, 0.f, 0.f};

  #pragma unroll 1
  for (int k = 0; k < 9; k++) {
    // ---- col GEMM for this k: permuted rows 64+k*64 .. 128+k*64 ----
    const int q = 1 + k, og = q >> 1, ocq = q & 1;
    f32x4 acc[2][2];
    #pragma unroll
    for (int mi = 0; mi < 2; mi++)
      #pragma unroll
      for (int ni = 0; ni < 2; ni++) acc[mi][ni] = (f32x4){0.f, 0.f, 0.f, 0.f};
    #pragma unroll 2
    for (int ks = 0; ks < 18; ks++) {
      const int kk = ks >> 1, half = ks & 1;
      const int dr = kk / 3, dc = kk - dr * 3;
      const ushort* wp8 = Wpk + ((size_t)((((og * 18 + ks) << 1) + ocq) << 11)) + (lane << 3);
      s16x8 af[2], bfr[2];
      #pragma unroll
      for (int mi = 0; mi < 2; mi++)
        af[mi] = *(const s16x8*)(wp8 + (((rowq << 1) + mi) << 9));
      const int gci = half * 4 + kb;
      #pragma unroll
      for (int ni = 0; ni < 2; ni++) {
        int r = (pxq << 5) + ni * 16 + nif;
        int w1 = r + dc;
        int slot = (gci + w1) & 7;
        bfr[ni] = *(const s16x8*)(sF + ((dr * 66 + w1) << 6) + slot * 8);
      }
      #pragma unroll
      for (int mi = 0; mi < 2; mi++)
        #pragma unroll
        for (int ni = 0; ni < 2; ni++)
          acc[mi][ni] = __builtin_amdgcn_mfma_f32_16x16x32_bf16(af[mi], bfr[ni], acc[mi][ni], 0, 0, 0);
    }
    __syncthreads();   // prior k's finalMFMA reads of colT complete (k=0: homT visible)

    // epilogue: tanh -> colT (slot-rotated), packed converts
    #pragma unroll
    for (int mi = 0; mi < 2; mi++) {
      #pragma unroll
      for (int ni = 0; ni < 2; ni++) {
        int px = (pxq << 5) + ni * 16 + nif;
        int c = (rowq << 5) + mi * 16 + (quad << 2);
        float4 b4 = *(const float4*)(Bc + 64 + (k << 6) + c);
        uint2 pk2;
        pk2.x = pkbf(fast_tanh(acc[mi][ni][0] + b4.x), fast_tanh(acc[mi][ni][1] + b4.y));
        pk2.y = pkbf(fast_tanh(acc[mi][ni][2] + b4.z), fast_tanh(acc[mi][ni][3] + b4.w));
        int slot = ((c >> 3) + px) & 7;
        *(uint2*)(colT + (px << 6) + slot * 8 + (c & 7)) = pk2;
      }
    }
    __syncthreads();   // colT visible to sampler

    // ---- sampler: 16 channels of pixel pxl, in-place update of colT ----
    {
      float ox = homT[pxl * 27 + k];
      float oy = homT[pxl * 27 + 9 + k];
      float mk = homT[pxl * 27 + 18 + k];
      float px_ = (float)(h + k / 3) + ox;
      float py_ = (float)(ww + k % 3) + oy;
      float fx = floorf(px_), fy = floorf(py_);
      float qltx = fminf(fmaxf(fx, 0.f), 129.f);
      float qlty = fminf(fmaxf(fy, 0.f), 129.f);
      float qrbx = fminf(fmaxf(fx + 1.f, 0.f), 129.f);
      float qrby = fminf(fmaxf(fy + 1.f, 0.f), 129.f);
      float sx = fminf(fmaxf(px_, 0.f), 129.f);
      float sy = fminf(fmaxf(py_, 0.f), 129.f);
      float ax = 1.f + qltx - sx, bx = 1.f - qrbx + sx;
      float ay = 1.f + qlty - sy, by = 1.f - qrby + sy;
      int iltx = (int)qltx, ilty = (int)qlty, irbx = (int)qrbx, irby = (int)qrby;
      bool vltx = (iltx >= 1) && (iltx <= 128);
      bool vlty = (ilty >= 1) && (ilty <= 128);
      bool vrbx = (irbx >= 1) && (irbx <= 128);
      bool vrby = (irby >= 1) && (irby <= 128);
      float wl[4];
      int   ofs[4];
      wl[0] = (vltx && vlty) ? ax * ay : 0.f;
      wl[1] = (vrbx && vrby) ? bx * by : 0.f;
      wl[2] = (vltx && vrby) ? ax * by : 0.f;
      wl[3] = (vrbx && vlty) ? bx * ay : 0.f;
      ofs[0] = (vltx && vlty) ? ((iltx - 1) << 7) + (ilty - 1) : 0;
      ofs[1] = (vrbx && vrby) ? ((irbx - 1) << 7) + (irby - 1) : 0;
      ofs[2] = (vltx && vrby) ? ((iltx - 1) << 7) + (irby - 1) : 0;
      ofs[3] = (vrbx && vlty) ? ((irbx - 1) << 7) + (ilty - 1) : 0;

      float pos[16];
      #pragma unroll
      for (int j = 0; j < 16; j++) pos[j] = 0.f;
      #pragma unroll
      for (int corner = 0; corner < 4; corner++) {
        const ushort* p = xb + ((size_t)ofs[corner] << 6) + c0;
        uint4 A  = *(const uint4*)(p);
        uint4 Bv = *(const uint4*)(p + 8);
        float wgt = wl[corner];
        pos[0]  += wgt * bflo(A.x);  pos[1]  += wgt * bfhi(A.x);
        pos[2]  += wgt * bflo(A.y);  pos[3]  += wgt * bfhi(A.y);
        pos[4]  += wgt * bflo(A.z);  pos[5]  += wgt * bfhi(A.z);
        pos[6]  += wgt * bflo(A.w);  pos[7]  += wgt * bfhi(A.w);
        pos[8]  += wgt * bflo(Bv.x); pos[9]  += wgt * bfhi(Bv.x);
        pos[10] += wgt * bflo(Bv.y); pos[11] += wgt * bfhi(Bv.y);
        pos[12] += wgt * bflo(Bv.z); pos[13] += wgt * bfhi(Bv.z);
        pos[14] += wgt * bflo(Bv.w); pos[15] += wgt * bfhi(Bv.w);
      }
      // read own col slots, update, write back (thread-exclusive -> no barrier)
      #pragma unroll
      for (int q2 = 0; q2 < 2; q2++) {
        int chunk = (cq << 1) + q2;
        int slot = (chunk + pxl) & 7;
        ushort* cp = colT + (pxl << 6) + slot * 8;
        uint4 cw = *(const uint4*)cp;
        float f0 = (bflo(cw.x) + pos[q2 * 8 + 0]) * mk;
        float f1 = (bfhi(cw.x) + pos[q2 * 8 + 1]) * mk;
        float f2 = (bflo(cw.y) + pos[q2 * 8 + 2]) * mk;
        float f3 = (bfhi(cw.y) + pos[q2 * 8 + 3]) * mk;
        float f4 = (bflo(cw.z) + pos[q2 * 8 + 4]) * mk;
        float f5 = (bfhi(cw.z) + pos[q2 * 8 + 5]) * mk;
        float f6 = (bflo(cw.w) + pos[q2 * 8 + 6]) * mk;
        float f7 = (bfhi(cw.w) + pos[q2 * 8 + 7]) * mk;
        uint4 ow;
        ow.x = pkbf(f0, f1);
        ow.y = pkbf(f2, f3);
        ow.z = pkbf(f4, f5);
        ow.w = pkbf(f6, f7);
        *(uint4*)cp = ow;
      }
    }
    __syncthreads();   // updated colT visible to MFMA

    // ---- final-GEMM MFMA: 2 ks-steps over this k-tile ----
    #pragma unroll
    for (int khalf = 0; khalf < 2; khalf++) {
      int ks2 = (k << 1) + khalf;
      s16x8 af[2], bfr[2];
      #pragma unroll
      for (int mi = 0; mi < 2; mi++)
        af[mi] = *(const s16x8*)(W2pk + ((((ks2 << 2) + (rowq << 1) + mi) << 6) + lane) * 8);
      const int g0 = (khalf << 2) + kb;
      #pragma unroll
      for (int ni = 0; ni < 2; ni++) {
        int r = (pxq << 5) + ni * 16 + nif;
        int slot = (g0 + r) & 7;
        bfr[ni] = *(const s16x8*)(colT + (r << 6) + slot * 8);
      }
      #pragma unroll
      for (int mi = 0; mi < 2; mi++)
        #pragma unroll
        for (int ni = 0; ni < 2; ni++)
          aco[mi][ni] = __builtin_amdgcn_mfma_f32_16x16x32_bf16(af[mi], bfr[ni], aco[mi][ni], 0, 0, 0);
    }
  }

  // ---- store out ----
  #pragma unroll
  for (int mi = 0; mi < 2; mi++) {
    #pragma unroll
    for (int ni = 0; ni < 2; ni++) {
      int hwp = hw0 + (pxq << 5) + ni * 16 + nif;
      #pragma unroll
      for (int r = 0; r < 4; r++) {
        int o = (rowq << 5) + mi * 16 + (quad << 2) + r;
        out[(((size_t)b * 64 + o) << 14) + hwp] = aco[mi][ni][r];
      }
    }
  }
}

extern "C" void kernel_launch(void* const* d_in, const int* in_sizes, int n_in,
                              void* d_out, int out_size, void* d_ws, size_t ws_size,
                              hipStream_t stream) {
  const float* x     = (const float*)d_in[0];
  const float* ref   = (const float*)d_in[1];
  const float* wcd   = (const float*)d_in[2];
  const float* bcd   = (const float*)d_in[3];
  const float* wp    = (const float*)d_in[4];
  const float* bp    = (const float*)d_in[5];
  const float* wm    = (const float*)d_in[6];
  const float* bm    = (const float*)d_in[7];
  const float* wc    = (const float*)d_in[8];
  const float* bc    = (const float*)d_in[9];
  const float* wconv = (const float*)d_in[10];
  float* out = (float*)d_out;

  char* w8 = (char*)d_ws;
  ushort* Wpk     = (ushort*)(w8 + 0);           //    737,280 B
  float*  Bc      = (float*)(w8 + 737280);       //      2,560 B
  ushort* W2pk    = (ushort*)(w8 + 739840);      //     73,728 B
  ushort* fusedt  = (ushort*)(w8 + 813568);      //  8,388,608 B (pixel-major)
  ushort* xtb     = (ushort*)(w8 + 9202176);     //  8,388,608 B -> total 17,590,784 B

  // blocks [0,1024): fused conv (MFMA) + xtb; blocks [1024,2464): weight packing
  k_fused <<<2464, 256, 0, stream>>>(x, ref, wcd, bcd, wp, bp, wm, bm, wc, bc, wconv,
                                     fusedt, xtb, Wpk, Bc, W2pk);
  k_all   <<<1024, 256, 0, stream>>>(Wpk, fusedt, Bc, xtb, W2pk, out);
}

// Round 10
// 199.197 us; speedup vs baseline: 1.1884x; 1.1884x over previous
//
#include <hip/hip_runtime.h>
#include <hip/hip_bf16.h>
#include <math.h>

typedef short s16x8 __attribute__((ext_vector_type(8)));
typedef float f32x4 __attribute__((ext_vector_type(4)));

__device__ inline ushort f2bf(float f) {
  unsigned u = __float_as_uint(f);
  u = (u + 0x7FFF + ((u >> 16) & 1)) >> 16;
  return (ushort)u;
}
__device__ inline float bf2f(ushort u) {
  return __uint_as_float(((unsigned)u) << 16);
}
// packed f32x2 -> bf16x2 RNE (bit-identical to f2bf pair)
__device__ inline unsigned pkbf(float a, float b) {
  __hip_bfloat162 h = __float22bfloat162_rn(make_float2(a, b));
  return *(unsigned*)&h;
}
// fast activations: v_exp_f32 + v_rcp_f32; saturate correctly at +/-inf.
__device__ inline float fast_tanh(float v) {
  float e = __builtin_amdgcn_exp2f(v * 2.8853900817779268f);   // exp(2v)
  return 1.f - 2.f * __builtin_amdgcn_rcpf(e + 1.f);
}
__device__ inline float fast_sigmoid(float v) {
  float e = __builtin_amdgcn_exp2f(v * -1.4426950408889634f);  // exp(-v)
  return __builtin_amdgcn_rcpf(1.f + e);
}

// ---- PERMUTED head-row space (640 rows):
//   g in [0,18): off | [18,27): mod | [27,64): pad | [64,640): col j=g-64=k*64+c
//     source col channel cc = c*9+k.
// ---- K1: fused 1x1 conv as MFMA GEMM -> fusedt[pix][64] bf16, xtb (natural order)
//      transpose as a free by-product of B-operand staging, PLUS weight packing
//      (former k_merge) on blocks >= 1024.
// Round-10: round-8 structure (NO ref reg-prefetch: its +16 held VGPRs regressed
// occupancy in round 9). Local-only tweaks: float4 wcd loads + pkbf packing
// (values consumed immediately -> no lifetime extension).
__global__ __launch_bounds__(256) void k_fused(
    const float* __restrict__ x, const float* __restrict__ ref,
    const float* __restrict__ wcd, const float* __restrict__ bcd,
    const float* __restrict__ wp, const float* __restrict__ bp,
    const float* __restrict__ wm, const float* __restrict__ bm,
    const float* __restrict__ wc, const float* __restrict__ bc,
    const float* __restrict__ wconv,
    ushort* __restrict__ fusedt, ushort* __restrict__ xtb,
    ushort* __restrict__ Wpk, float* __restrict__ Bc, ushort* __restrict__ W2pk) {
  __shared__ float sxf[64][68];                       // 17,408 B (pad 68: b128-aligned)
  __shared__ __align__(16) ushort w_lds[64 * 128];    // 16,384 B  A: [oc][16 chunks]
  __shared__ __align__(16) ushort xt_lds[64 * 128];   // 16,384 B  B: [px][16 chunks]
  __shared__ float sb[64];

  if (blockIdx.x >= 1024) {
    // ---- weight-packing blocks (former k_merge), 1440 blocks ----
    int i = (blockIdx.x - 1024) * 256 + threadIdx.x;
    if (i < 368640) {
      int e = i & 7, lane = (i >> 3) & 63, mi = (i >> 9) & 3, ocq = (i >> 11) & 1;
      int hi = i >> 12;                 // 0..89
      int ks = hi % 18, og = hi / 18;
      int g = og * 128 + ocq * 64 + mi * 16 + (lane & 15);
      int ci = ((ks & 1) << 5) + ((lane >> 4) << 3) + e;
      int kk = ks >> 1;
      int col = ci * 9 + kk;
      float v = 0.f;
      if (g < 18)       v = wp[g * 576 + col];
      else if (g < 27)  v = wm[(g - 18) * 576 + col];
      else if (g >= 64) {
        int j = g - 64;
        int cc = (j & 63) * 9 + (j >> 6);
        v = wc[cc * 576 + col];
      }
      Wpk[i] = f2bf(v);
    }
    if (i < 36864) {
      int e = i & 7, lane = (i >> 3) & 63, mi = (i >> 9) & 3, ks = i >> 11;  // 0..17
      int o = mi * 16 + (lane & 15);
      int p = (ks << 5) + ((lane >> 4) << 3) + e;
      int kk2 = p >> 6, c = p & 63;
      W2pk[i] = f2bf(wconv[o * 576 + c * 9 + kk2]);
    }
    if (i < 640) {
      float bv = 0.f;
      if (i < 18)       bv = bp[i];
      else if (i < 27)  bv = bm[i - 18];
      else if (i >= 64) {
        int j = i - 64;
        bv = bc[(j & 63) * 9 + (j >> 6)];
      }
      Bc[i] = bv;
    }
    return;
  }

  // ---- conv blocks: 64 px each ----
  const int t = threadIdx.x;
  const int b = blockIdx.x >> 8, hw0 = (blockIdx.x & 255) << 6;
  if (t < 64) sb[t] = bcd[t];

  // A-operand: w_lds[oc][chunk g slot-rotated], natural K-order; float4 loads + pkbf.
  #pragma unroll
  for (int rep = 0; rep < 4; rep++) {
    int idx = t + (rep << 8);              // 0..1023 = oc*16 + g
    int oc = idx >> 4, g = idx & 15;
    const float4* wr4 = (const float4*)(wcd + oc * 128 + (g << 3));
    float4 wa = wr4[0], wb2 = wr4[1];
    uint4 ow;
    ow.x = pkbf(wa.x, wa.y);   ow.y = pkbf(wa.z, wa.w);
    ow.z = pkbf(wb2.x, wb2.y); ow.w = pkbf(wb2.z, wb2.w);
    *(uint4*)(w_lds + oc * 128 + (((g + oc) & 15) << 3)) = ow;
  }

  // stage x tile fp32 (coalesced float4)
  #pragma unroll
  for (int rep = 0; rep < 4; rep++) {
    int idx = t + (rep << 8);              // 0..1023 float4s
    int ci = idx >> 4, p4 = (idx & 15) << 2;
    float4 v = *(const float4*)(x + ((size_t)((b << 6) + ci) << 14) + hw0 + p4);
    *(float4*)&sxf[ci][p4] = v;
  }
  __syncthreads();

  // build B x-half (chunks 0..7, natural); rows == xtb rows -> free global transpose
  #pragma unroll
  for (int rep = 0; rep < 2; rep++) {
    int idx = t + (rep << 8);              // 0..511 = px*8 + g
    int px = idx >> 3, g = idx & 7;
    const int e0 = g << 3;
    uint4 ow;
    ow.x = pkbf(sxf[e0 + 0][px], sxf[e0 + 1][px]);
    ow.y = pkbf(sxf[e0 + 2][px], sxf[e0 + 3][px]);
    ow.z = pkbf(sxf[e0 + 4][px], sxf[e0 + 5][px]);
    ow.w = pkbf(sxf[e0 + 6][px], sxf[e0 + 7][px]);
    *(uint4*)(xt_lds + px * 128 + (((g + px) & 15) << 3)) = ow;
    *(uint4*)(xtb + (((size_t)b << 14) + hw0 + px) * 64 + (g << 3)) = ow;
  }
  __syncthreads();   // all sxf(x) reads done before overwrite

  // stage ref tile fp32
  #pragma unroll
  for (int rep = 0; rep < 4; rep++) {
    int idx = t + (rep << 8);
    int ci = idx >> 4, p4 = (idx & 15) << 2;
    float4 v = *(const float4*)(ref + ((size_t)((b << 6) + ci) << 14) + hw0 + p4);
    *(float4*)&sxf[ci][p4] = v;
  }
  __syncthreads();

  // build B ref-half (chunks 8..15, natural)
  #pragma unroll
  for (int rep = 0; rep < 2; rep++) {
    int idx = t + (rep << 8);
    int px = idx >> 3, g = (idx & 7) + 8;
    const int e0 = (g & 7) << 3;
    uint4 ow;
    ow.x = pkbf(sxf[e0 + 0][px], sxf[e0 + 1][px]);
    ow.y = pkbf(sxf[e0 + 2][px], sxf[e0 + 3][px]);
    ow.z = pkbf(sxf[e0 + 4][px], sxf[e0 + 5][px]);
    ow.w = pkbf(sxf[e0 + 6][px], sxf[e0 + 7][px]);
    *(uint4*)(xt_lds + px * 128 + (((g + px) & 15) << 3)) = ow;
  }
  __syncthreads();

  // GEMM: wave -> 16 oc, 4 ni x 4 ksteps MFMAs
  const int lane = t & 63, wv4 = t >> 6;
  const int ocl = lane & 15, kb = lane >> 4;
  const int ocr = (wv4 << 4) + ocl;
  f32x4 acc[4];
  #pragma unroll
  for (int ni = 0; ni < 4; ni++) acc[ni] = (f32x4){0.f, 0.f, 0.f, 0.f};
  #pragma unroll
  for (int s = 0; s < 4; s++) {
    const int gA = (s << 2) + kb;
    s16x8 af = *(const s16x8*)(w_lds + ocr * 128 + (((gA + ocr) & 15) << 3));
    #pragma unroll
    for (int ni = 0; ni < 4; ni++) {
      const int px = (ni << 4) + ocl;
      s16x8 bf8 = *(const s16x8*)(xt_lds + px * 128 + (((gA + px) & 15) << 3));
      acc[ni] = __builtin_amdgcn_mfma_f32_16x16x32_bf16(af, bf8, acc[ni], 0, 0, 0);
    }
  }
  // epilogue: +bias, pack bf16, store fusedt[pix][oc]
  const float4 b4 = *(const float4*)&sb[(wv4 << 4) + (kb << 2)];
  #pragma unroll
  for (int ni = 0; ni < 4; ni++) {
    const int px = (ni << 4) + ocl;
    uint2 o;
    o.x = pkbf(acc[ni][0] + b4.x, acc[ni][1] + b4.y);
    o.y = pkbf(acc[ni][2] + b4.z, acc[ni][3] + b4.w);
    *(uint2*)(fusedt + (((size_t)(b << 14) + hw0 + px) << 6) + (wv4 << 4) + (kb << 2)) = o;
  }
}

// ---- K3: FULLY FUSED head-GEMM + sampler + final GEMM, 64-px tiles --------------------
// BYTE-EXACT round-8 version (116 us, VGPR 64, proven). Do NOT touch: round-9's
// "register-neutral" pkbf swap pushed VGPR 64->68 and crossed the 64-VGPR wave
// allocation cliff (occupancy 38->23%, +27 us). k_all is pinned to the <=64-VGPR,
// recompute-heavy regime.
// grid 1024; block 256 = 4 waves; 4 blocks/CU (LDS 40,448B).
__global__ __launch_bounds__(256) void k_all(
    const ushort* __restrict__ Wpk, const ushort* __restrict__ fusedt,
    const float* __restrict__ Bc, const ushort* __restrict__ xtb,
    const ushort* __restrict__ W2pk, float* __restrict__ out) {
  __shared__ __align__(16) ushort sF[3 * 66 * 64];    // 25,344 B
  __shared__ __align__(16) ushort colT[64 * 64];      //  8,192 B
  __shared__ float homT[64 * 27];                     //  6,912 B
  const int t = threadIdx.x;
  const int lane = t & 63, wv = t >> 6;
  const int rowid = blockIdx.x;           // b*256 + h*2 + half
  const int b = rowid >> 8;
  const int rem = rowid & 255;
  const int h = rem >> 1, hf = rem & 1;
  const int w0 = hf << 6;
  const int hw0 = (h << 7) + w0;

  // stage fused rows h-1..h+1, w1 in [0,66) covering gw in [w0-1, w0+64]
  for (int idx = t; idx < 1584; idx += 256) {   // 198 pixels x 8 ci-chunks
    int p = idx >> 3, j = idx & 7;
    int row = p / 66, w1 = p - row * 66;
    int gh = h + row - 1, gw = w0 + w1 - 1;
    uint4 v = make_uint4(0u, 0u, 0u, 0u);
    if (gh >= 0 && gh < 128 && (unsigned)gw < 128u)
      v = *(const uint4*)(fusedt + ((size_t)((b << 14) + (gh << 7) + gw) << 6) + j * 8);
    int slot = (j + w1) & 7;
    *(uint4*)(sF + (p << 6) + slot * 8) = v;
  }
  __syncthreads();

  const int pxq = wv & 1, rowq = wv >> 1;
  const int nif = lane & 15, kb = lane >> 4, quad = lane >> 4;

  // ---- off/mod GEMM: permuted rows 0..31 (rowq==0 waves only) ----
  if (rowq == 0) {
    f32x4 acc[2][2];
    #pragma unroll
    for (int mi = 0; mi < 2; mi++)
      #pragma unroll
      for (int ni = 0; ni < 2; ni++) acc[mi][ni] = (f32x4){0.f, 0.f, 0.f, 0.f};
    #pragma unroll 2
    for (int ks = 0; ks < 18; ks++) {
      const int kk = ks >> 1, half = ks & 1;
      const int dr = kk / 3, dc = kk - dr * 3;
      const ushort* wp8 = Wpk + ((size_t)(ks << 12)) + (lane << 3);  // og=0, ocq=0
      s16x8 af[2], bfr[2];
      #pragma unroll
      for (int mi = 0; mi < 2; mi++)
        af[mi] = *(const s16x8*)(wp8 + (mi << 9));
      const int gci = half * 4 + kb;
      #pragma unroll
      for (int ni = 0; ni < 2; ni++) {
        int r = (pxq << 5) + ni * 16 + nif;
        int w1 = r + dc;
        int slot = (gci + w1) & 7;
        bfr[ni] = *(const s16x8*)(sF + ((dr * 66 + w1) << 6) + slot * 8);
      }
      #pragma unroll
      for (int mi = 0; mi < 2; mi++)
        #pragma unroll
        for (int ni = 0; ni < 2; ni++)
          acc[mi][ni] = __builtin_amdgcn_mfma_f32_16x16x32_bf16(af[mi], bfr[ni], acc[mi][ni], 0, 0, 0);
    }
    #pragma unroll
    for (int mi = 0; mi < 2; mi++) {
      #pragma unroll
      for (int ni = 0; ni < 2; ni++) {
        int px = (pxq << 5) + ni * 16 + nif;
        #pragma unroll
        for (int r = 0; r < 4; r++) {
          int g = mi * 16 + (quad << 2) + r;
          float v = acc[mi][ni][r] + Bc[g];
          if (g < 18)       homT[px * 27 + g] = v;
          else if (g < 27)  homT[px * 27 + g] = fast_sigmoid(v);
        }
      }
    }
  }

  // sampler per-pixel identity: 4 thr/px x 16 ch
  const int cq = t >> 6, pxl = t & 63, c0 = cq << 4;
  const int ww = w0 + pxl;
  const ushort* xb = xtb + ((size_t)b << 20);

  f32x4 aco[2][2];
  #pragma unroll
  for (int mi = 0; mi < 2; mi++)
    #pragma unroll
    for (int ni = 0; ni < 2; ni++) aco[mi][ni] = (f32x4){0.f, 0.f, 0.f, 0.f};

  #pragma unroll 1
  for (int k = 0; k < 9; k++) {
    // ---- col GEMM for this k: permuted rows 64+k*64 .. 128+k*64 ----
    const int q = 1 + k, og = q >> 1, ocq = q & 1;
    f32x4 acc[2][2];
    #pragma unroll
    for (int mi = 0; mi < 2; mi++)
      #pragma unroll
      for (int ni = 0; ni < 2; ni++) acc[mi][ni] = (f32x4){0.f, 0.f, 0.f, 0.f};
    #pragma unroll 2
    for (int ks = 0; ks < 18; ks++) {
      const int kk = ks >> 1, half = ks & 1;
      const int dr = kk / 3, dc = kk - dr * 3;
      const ushort* wp8 = Wpk + ((size_t)((((og * 18 + ks) << 1) + ocq) << 11)) + (lane << 3);
      s16x8 af[2], bfr[2];
      #pragma unroll
      for (int mi = 0; mi < 2; mi++)
        af[mi] = *(const s16x8*)(wp8 + (((rowq << 1) + mi) << 9));
      const int gci = half * 4 + kb;
      #pragma unroll
      for (int ni = 0; ni < 2; ni++) {
        int r = (pxq << 5) + ni * 16 + nif;
        int w1 = r + dc;
        int slot = (gci + w1) & 7;
        bfr[ni] = *(const s16x8*)(sF + ((dr * 66 + w1) << 6) + slot * 8);
      }
      #pragma unroll
      for (int mi = 0; mi < 2; mi++)
        #pragma unroll
        for (int ni = 0; ni < 2; ni++)
          acc[mi][ni] = __builtin_amdgcn_mfma_f32_16x16x32_bf16(af[mi], bfr[ni], acc[mi][ni], 0, 0, 0);
    }
    __syncthreads();   // prior k's finalMFMA reads of colT complete (k=0: homT visible)

    // epilogue: tanh -> colT (slot-rotated)
    #pragma unroll
    for (int mi = 0; mi < 2; mi++) {
      #pragma unroll
      for (int ni = 0; ni < 2; ni++) {
        int px = (pxq << 5) + ni * 16 + nif;
        int c = (rowq << 5) + mi * 16 + (quad << 2);
        float4 b4 = *(const float4*)(Bc + 64 + (k << 6) + c);
        ushort v4[4];
        v4[0] = f2bf(fast_tanh(acc[mi][ni][0] + b4.x));
        v4[1] = f2bf(fast_tanh(acc[mi][ni][1] + b4.y));
        v4[2] = f2bf(fast_tanh(acc[mi][ni][2] + b4.z));
        v4[3] = f2bf(fast_tanh(acc[mi][ni][3] + b4.w));
        int slot = ((c >> 3) + px) & 7;
        *(uint2*)(colT + (px << 6) + slot * 8 + (c & 7)) = *(uint2*)v4;
      }
    }
    __syncthreads();   // colT visible to sampler

    // ---- sampler: 16 channels of pixel pxl, in-place update of colT ----
    {
      float ox = homT[pxl * 27 + k];
      float oy = homT[pxl * 27 + 9 + k];
      float mk = homT[pxl * 27 + 18 + k];
      float px_ = (float)(h + k / 3) + ox;
      float py_ = (float)(ww + k % 3) + oy;
      float fx = floorf(px_), fy = floorf(py_);
      float qltx = fminf(fmaxf(fx, 0.f), 129.f);
      float qlty = fminf(fmaxf(fy, 0.f), 129.f);
      float qrbx = fminf(fmaxf(fx + 1.f, 0.f), 129.f);
      float qrby = fminf(fmaxf(fy + 1.f, 0.f), 129.f);
      float sx = fminf(fmaxf(px_, 0.f), 129.f);
      float sy = fminf(fmaxf(py_, 0.f), 129.f);
      float ax = 1.f + qltx - sx, bx = 1.f - qrbx + sx;
      float ay = 1.f + qlty - sy, by = 1.f - qrby + sy;
      int iltx = (int)qltx, ilty = (int)qlty, irbx = (int)qrbx, irby = (int)qrby;
      bool vltx = (iltx >= 1) && (iltx <= 128);
      bool vlty = (ilty >= 1) && (ilty <= 128);
      bool vrbx = (irbx >= 1) && (irbx <= 128);
      bool vrby = (irby >= 1) && (irby <= 128);
      float wl[4];
      int   ofs[4];
      wl[0] = (vltx && vlty) ? ax * ay : 0.f;
      wl[1] = (vrbx && vrby) ? bx * by : 0.f;
      wl[2] = (vltx && vrby) ? ax * by : 0.f;
      wl[3] = (vrbx && vlty) ? bx * ay : 0.f;
      ofs[0] = (vltx && vlty) ? ((iltx - 1) << 7) + (ilty - 1) : 0;
      ofs[1] = (vrbx && vrby) ? ((irbx - 1) << 7) + (irby - 1) : 0;
      ofs[2] = (vltx && vrby) ? ((iltx - 1) << 7) + (irby - 1) : 0;
      ofs[3] = (vrbx && vlty) ? ((irbx - 1) << 7) + (ilty - 1) : 0;

      float pos[16];
      #pragma unroll
      for (int j = 0; j < 16; j++) pos[j] = 0.f;
      #pragma unroll
      for (int corner = 0; corner < 4; corner++) {
        const ushort* p = xb + ((size_t)ofs[corner] << 6) + c0;
        float wgt = wl[corner];
        ushort tmp[16];
        *(uint4*)(tmp)     = *(const uint4*)(p);
        *(uint4*)(tmp + 8) = *(const uint4*)(p + 8);
        #pragma unroll
        for (int j = 0; j < 16; j++) pos[j] += wgt * bf2f(tmp[j]);
      }
      // read own col slots, update, write back (thread-exclusive -> no barrier)
      #pragma unroll
      for (int q2 = 0; q2 < 2; q2++) {
        int chunk = (cq << 1) + q2;
        int slot = (chunk + pxl) & 7;
        ushort* cp = colT + (pxl << 6) + slot * 8;
        ushort ct[8];
        *(uint4*)ct = *(const uint4*)cp;
        #pragma unroll
        for (int j = 0; j < 8; j++)
          ct[j] = f2bf((bf2f(ct[j]) + pos[q2 * 8 + j]) * mk);
        *(uint4*)cp = *(uint4*)ct;
      }
    }
    __syncthreads();   // updated colT visible to MFMA

    // ---- final-GEMM MFMA: 2 ks-steps over this k-tile ----
    #pragma unroll
    for (int khalf = 0; khalf < 2; khalf++) {
      int ks2 = (k << 1) + khalf;
      s16x8 af[2], bfr[2];
      #pragma unroll
      for (int mi = 0; mi < 2; mi++)
        af[mi] = *(const s16x8*)(W2pk + ((((ks2 << 2) + (rowq << 1) + mi) << 6) + lane) * 8);
      const int g0 = (khalf << 2) + kb;
      #pragma unroll
      for (int ni = 0; ni < 2; ni++) {
        int r = (pxq << 5) + ni * 16 + nif;
        int slot = (g0 + r) & 7;
        bfr[ni] = *(const s16x8*)(colT + (r << 6) + slot * 8);
      }
      #pragma unroll
      for (int mi = 0; mi < 2; mi++)
        #pragma unroll
        for (int ni = 0; ni < 2; ni++)
          aco[mi][ni] = __builtin_amdgcn_mfma_f32_16x16x32_bf16(af[mi], bfr[ni], aco[mi][ni], 0, 0, 0);
    }
  }

  // ---- store out ----
  #pragma unroll
  for (int mi = 0; mi < 2; mi++) {
    #pragma unroll
    for (int ni = 0; ni < 2; ni++) {
      int hwp = hw0 + (pxq << 5) + ni * 16 + nif;
      #pragma unroll
      for (int r = 0; r < 4; r++) {
        int o = (rowq << 5) + mi * 16 + (quad << 2) + r;
        out[(((size_t)b * 64 + o) << 14) + hwp] = aco[mi][ni][r];
      }
    }
  }
}

extern "C" void kernel_launch(void* const* d_in, const int* in_sizes, int n_in,
                              void* d_out, int out_size, void* d_ws, size_t ws_size,
                              hipStream_t stream) {
  const float* x     = (const float*)d_in[0];
  const float* ref   = (const float*)d_in[1];
  const float* wcd   = (const float*)d_in[2];
  const float* bcd   = (const float*)d_in[3];
  const float* wp    = (const float*)d_in[4];
  const float* bp    = (const float*)d_in[5];
  const float* wm    = (const float*)d_in[6];
  const float* bm    = (const float*)d_in[7];
  const float* wc    = (const float*)d_in[8];
  const float* bc    = (const float*)d_in[9];
  const float* wconv = (const float*)d_in[10];
  float* out = (float*)d_out;

  char* w8 = (char*)d_ws;
  ushort* Wpk     = (ushort*)(w8 + 0);           //    737,280 B
  float*  Bc      = (float*)(w8 + 737280);       //      2,560 B
  ushort* W2pk    = (ushort*)(w8 + 739840);      //     73,728 B
  ushort* fusedt  = (ushort*)(w8 + 813568);      //  8,388,608 B (pixel-major)
  ushort* xtb     = (ushort*)(w8 + 9202176);     //  8,388,608 B -> total 17,590,784 B

  // blocks [0,1024): fused conv (MFMA) + xtb; blocks [1024,2464): weight packing
  k_fused <<<2464, 256, 0, stream>>>(x, ref, wcd, bcd, wp, bp, wm, bm, wc, bc, wconv,
                                     fusedt, xtb, Wpk, Bc, W2pk);
  k_all   <<<1024, 256, 0, stream>>>(Wpk, fusedt, Bc, xtb, W2pk, out);
}

// Round 11
// 198.177 us; speedup vs baseline: 1.1945x; 1.0051x over previous
//
#include <hip/hip_runtime.h>
#include <hip/hip_bf16.h>
#include <math.h>

typedef short s16x8 __attribute__((ext_vector_type(8)));
typedef float f32x4 __attribute__((ext_vector_type(4)));

__device__ inline ushort f2bf(float f) {
  unsigned u = __float_as_uint(f);
  u = (u + 0x7FFF + ((u >> 16) & 1)) >> 16;
  return (ushort)u;
}
__device__ inline float bf2f(ushort u) {
  return __uint_as_float(((unsigned)u) << 16);
}
// packed f32x2 -> bf16x2 RNE (bit-identical to f2bf pair)
__device__ inline unsigned pkbf(float a, float b) {
  __hip_bfloat162 h = __float22bfloat162_rn(make_float2(a, b));
  return *(unsigned*)&h;
}
// fast activations: v_exp_f32 + v_rcp_f32; saturate correctly at +/-inf.
__device__ inline float fast_tanh(float v) {
  float e = __builtin_amdgcn_exp2f(v * 2.8853900817779268f);   // exp(2v)
  return 1.f - 2.f * __builtin_amdgcn_rcpf(e + 1.f);
}
__device__ inline float fast_sigmoid(float v) {
  float e = __builtin_amdgcn_exp2f(v * -1.4426950408889634f);  // exp(-v)
  return __builtin_amdgcn_rcpf(1.f + e);
}

// ---- PERMUTED head-row space (640 rows):
//   g in [0,18): off | [18,27): mod | [27,64): pad | [64,640): col j=g-64=k*64+c
//     source col channel cc = c*9+k.
// ---- K1: fused 1x1 conv as MFMA GEMM -> fusedt[pix][64] bf16, xtb (natural order)
//      transpose as a free by-product of B-operand staging, PLUS weight packing
//      (former k_merge) on blocks >= 1024.
// Round-11: w_lds ELIMINATED -- wcd is 32KB and identical for all blocks (L2-hot), so
// A-fragments are built from global float4s at GEMM time. LDS 50,432 -> 34,048 B
// => 4 blocks/CU (was 3). One fewer LDS-write pass; values bit-identical.
__global__ __launch_bounds__(256) void k_fused(
    const float* __restrict__ x, const float* __restrict__ ref,
    const float* __restrict__ wcd, const float* __restrict__ bcd,
    const float* __restrict__ wp, const float* __restrict__ bp,
    const float* __restrict__ wm, const float* __restrict__ bm,
    const float* __restrict__ wc, const float* __restrict__ bc,
    const float* __restrict__ wconv,
    ushort* __restrict__ fusedt, ushort* __restrict__ xtb,
    ushort* __restrict__ Wpk, float* __restrict__ Bc, ushort* __restrict__ W2pk) {
  __shared__ float sxf[64][68];                       // 17,408 B (pad 68: b128-aligned)
  __shared__ __align__(16) ushort xt_lds[64 * 128];   // 16,384 B  B: [px][16 chunks]
  __shared__ float sb[64];                            // -> 34,048 B total, 4 blocks/CU

  if (blockIdx.x >= 1024) {
    // ---- weight-packing blocks (former k_merge), 1440 blocks ----
    int i = (blockIdx.x - 1024) * 256 + threadIdx.x;
    if (i < 368640) {
      int e = i & 7, lane = (i >> 3) & 63, mi = (i >> 9) & 3, ocq = (i >> 11) & 1;
      int hi = i >> 12;                 // 0..89
      int ks = hi % 18, og = hi / 18;
      int g = og * 128 + ocq * 64 + mi * 16 + (lane & 15);
      int ci = ((ks & 1) << 5) + ((lane >> 4) << 3) + e;
      int kk = ks >> 1;
      int col = ci * 9 + kk;
      float v = 0.f;
      if (g < 18)       v = wp[g * 576 + col];
      else if (g < 27)  v = wm[(g - 18) * 576 + col];
      else if (g >= 64) {
        int j = g - 64;
        int cc = (j & 63) * 9 + (j >> 6);
        v = wc[cc * 576 + col];
      }
      Wpk[i] = f2bf(v);
    }
    if (i < 36864) {
      int e = i & 7, lane = (i >> 3) & 63, mi = (i >> 9) & 3, ks = i >> 11;  // 0..17
      int o = mi * 16 + (lane & 15);
      int p = (ks << 5) + ((lane >> 4) << 3) + e;
      int kk2 = p >> 6, c = p & 63;
      W2pk[i] = f2bf(wconv[o * 576 + c * 9 + kk2]);
    }
    if (i < 640) {
      float bv = 0.f;
      if (i < 18)       bv = bp[i];
      else if (i < 27)  bv = bm[i - 18];
      else if (i >= 64) {
        int j = i - 64;
        bv = bc[(j & 63) * 9 + (j >> 6)];
      }
      Bc[i] = bv;
    }
    return;
  }

  // ---- conv blocks: 64 px each ----
  const int t = threadIdx.x;
  const int b = blockIdx.x >> 8, hw0 = (blockIdx.x & 255) << 6;
  if (t < 64) sb[t] = bcd[t];

  // stage x tile fp32 (coalesced float4)
  #pragma unroll
  for (int rep = 0; rep < 4; rep++) {
    int idx = t + (rep << 8);              // 0..1023 float4s
    int ci = idx >> 4, p4 = (idx & 15) << 2;
    float4 v = *(const float4*)(x + ((size_t)((b << 6) + ci) << 14) + hw0 + p4);
    *(float4*)&sxf[ci][p4] = v;
  }
  __syncthreads();

  // build B x-half (chunks 0..7, natural); rows == xtb rows -> free global transpose
  #pragma unroll
  for (int rep = 0; rep < 2; rep++) {
    int idx = t + (rep << 8);              // 0..511 = px*8 + g
    int px = idx >> 3, g = idx & 7;
    const int e0 = g << 3;
    uint4 ow;
    ow.x = pkbf(sxf[e0 + 0][px], sxf[e0 + 1][px]);
    ow.y = pkbf(sxf[e0 + 2][px], sxf[e0 + 3][px]);
    ow.z = pkbf(sxf[e0 + 4][px], sxf[e0 + 5][px]);
    ow.w = pkbf(sxf[e0 + 6][px], sxf[e0 + 7][px]);
    *(uint4*)(xt_lds + px * 128 + (((g + px) & 15) << 3)) = ow;
    *(uint4*)(xtb + (((size_t)b << 14) + hw0 + px) * 64 + (g << 3)) = ow;
  }
  __syncthreads();   // all sxf(x) reads done before overwrite

  // stage ref tile fp32
  #pragma unroll
  for (int rep = 0; rep < 4; rep++) {
    int idx = t + (rep << 8);
    int ci = idx >> 4, p4 = (idx & 15) << 2;
    float4 v = *(const float4*)(ref + ((size_t)((b << 6) + ci) << 14) + hw0 + p4);
    *(float4*)&sxf[ci][p4] = v;
  }
  __syncthreads();

  // build B ref-half (chunks 8..15, natural)
  #pragma unroll
  for (int rep = 0; rep < 2; rep++) {
    int idx = t + (rep << 8);
    int px = idx >> 3, g = (idx & 7) + 8;
    const int e0 = (g & 7) << 3;
    uint4 ow;
    ow.x = pkbf(sxf[e0 + 0][px], sxf[e0 + 1][px]);
    ow.y = pkbf(sxf[e0 + 2][px], sxf[e0 + 3][px]);
    ow.z = pkbf(sxf[e0 + 4][px], sxf[e0 + 5][px]);
    ow.w = pkbf(sxf[e0 + 6][px], sxf[e0 + 7][px]);
    *(uint4*)(xt_lds + px * 128 + (((g + px) & 15) << 3)) = ow;
  }
  __syncthreads();

  // GEMM: wave -> 16 oc, 4 ni x 4 ksteps MFMAs; A-fragments from global (L2-hot)
  const int lane = t & 63, wv4 = t >> 6;
  const int ocl = lane & 15, kb = lane >> 4;
  const int ocr = (wv4 << 4) + ocl;
  f32x4 acc[4];
  #pragma unroll
  for (int ni = 0; ni < 4; ni++) acc[ni] = (f32x4){0.f, 0.f, 0.f, 0.f};
  #pragma unroll
  for (int s = 0; s < 4; s++) {
    const int gA = (s << 2) + kb;
    const float4* wr4 = (const float4*)(wcd + ocr * 128 + (gA << 3));
    float4 wa = wr4[0], wb2 = wr4[1];
    unsigned aw[4];
    aw[0] = pkbf(wa.x, wa.y);   aw[1] = pkbf(wa.z, wa.w);
    aw[2] = pkbf(wb2.x, wb2.y); aw[3] = pkbf(wb2.z, wb2.w);
    s16x8 af = *(const s16x8*)aw;
    #pragma unroll
    for (int ni = 0; ni < 4; ni++) {
      const int px = (ni << 4) + ocl;
      s16x8 bf8 = *(const s16x8*)(xt_lds + px * 128 + (((gA + px) & 15) << 3));
      acc[ni] = __builtin_amdgcn_mfma_f32_16x16x32_bf16(af, bf8, acc[ni], 0, 0, 0);
    }
  }
  // epilogue: +bias, pack bf16, store fusedt[pix][oc]
  const float4 b4 = *(const float4*)&sb[(wv4 << 4) + (kb << 2)];
  #pragma unroll
  for (int ni = 0; ni < 4; ni++) {
    const int px = (ni << 4) + ocl;
    uint2 o;
    o.x = pkbf(acc[ni][0] + b4.x, acc[ni][1] + b4.y);
    o.y = pkbf(acc[ni][2] + b4.z, acc[ni][3] + b4.w);
    *(uint2*)(fusedt + (((size_t)(b << 14) + hw0 + px) << 6) + (wv4 << 4) + (kb << 2)) = o;
  }
}

// ---- K3: FULLY FUSED head-GEMM + sampler + final GEMM, 64-px tiles --------------------
// Round-8/10 structure (112-116 us, VGPR 64 -- the <=64-VGPR recompute-heavy regime is
// load-bearing; round-9's +4 VGPR cost 27 us). Round-11 delta: ONLY s_setprio(1)/(0)
// around the MFMA clusters (T5) -- SALU-only, zero registers. With 4 blocks/CU at
// different k-phases, MFMA-phase waves preempt sampler-phase waves' issue slots.
// grid 1024; block 256 = 4 waves; 4 blocks/CU (LDS 40,448B).
__global__ __launch_bounds__(256) void k_all(
    const ushort* __restrict__ Wpk, const ushort* __restrict__ fusedt,
    const float* __restrict__ Bc, const ushort* __restrict__ xtb,
    const ushort* __restrict__ W2pk, float* __restrict__ out) {
  __shared__ __align__(16) ushort sF[3 * 66 * 64];    // 25,344 B
  __shared__ __align__(16) ushort colT[64 * 64];      //  8,192 B
  __shared__ float homT[64 * 27];                     //  6,912 B
  const int t = threadIdx.x;
  const int lane = t & 63, wv = t >> 6;
  const int rowid = blockIdx.x;           // b*256 + h*2 + half
  const int b = rowid >> 8;
  const int rem = rowid & 255;
  const int h = rem >> 1, hf = rem & 1;
  const int w0 = hf << 6;
  const int hw0 = (h << 7) + w0;

  // stage fused rows h-1..h+1, w1 in [0,66) covering gw in [w0-1, w0+64]
  for (int idx = t; idx < 1584; idx += 256) {   // 198 pixels x 8 ci-chunks
    int p = idx >> 3, j = idx & 7;
    int row = p / 66, w1 = p - row * 66;
    int gh = h + row - 1, gw = w0 + w1 - 1;
    uint4 v = make_uint4(0u, 0u, 0u, 0u);
    if (gh >= 0 && gh < 128 && (unsigned)gw < 128u)
      v = *(const uint4*)(fusedt + ((size_t)((b << 14) + (gh << 7) + gw) << 6) + j * 8);
    int slot = (j + w1) & 7;
    *(uint4*)(sF + (p << 6) + slot * 8) = v;
  }
  __syncthreads();

  const int pxq = wv & 1, rowq = wv >> 1;
  const int nif = lane & 15, kb = lane >> 4, quad = lane >> 4;

  // ---- off/mod GEMM: permuted rows 0..31 (rowq==0 waves only) ----
  if (rowq == 0) {
    f32x4 acc[2][2];
    #pragma unroll
    for (int mi = 0; mi < 2; mi++)
      #pragma unroll
      for (int ni = 0; ni < 2; ni++) acc[mi][ni] = (f32x4){0.f, 0.f, 0.f, 0.f};
    __builtin_amdgcn_s_setprio(1);
    #pragma unroll 2
    for (int ks = 0; ks < 18; ks++) {
      const int kk = ks >> 1, half = ks & 1;
      const int dr = kk / 3, dc = kk - dr * 3;
      const ushort* wp8 = Wpk + ((size_t)(ks << 12)) + (lane << 3);  // og=0, ocq=0
      s16x8 af[2], bfr[2];
      #pragma unroll
      for (int mi = 0; mi < 2; mi++)
        af[mi] = *(const s16x8*)(wp8 + (mi << 9));
      const int gci = half * 4 + kb;
      #pragma unroll
      for (int ni = 0; ni < 2; ni++) {
        int r = (pxq << 5) + ni * 16 + nif;
        int w1 = r + dc;
        int slot = (gci + w1) & 7;
        bfr[ni] = *(const s16x8*)(sF + ((dr * 66 + w1) << 6) + slot * 8);
      }
      #pragma unroll
      for (int mi = 0; mi < 2; mi++)
        #pragma unroll
        for (int ni = 0; ni < 2; ni++)
          acc[mi][ni] = __builtin_amdgcn_mfma_f32_16x16x32_bf16(af[mi], bfr[ni], acc[mi][ni], 0, 0, 0);
    }
    __builtin_amdgcn_s_setprio(0);
    #pragma unroll
    for (int mi = 0; mi < 2; mi++) {
      #pragma unroll
      for (int ni = 0; ni < 2; ni++) {
        int px = (pxq << 5) + ni * 16 + nif;
        #pragma unroll
        for (int r = 0; r < 4; r++) {
          int g = mi * 16 + (quad << 2) + r;
          float v = acc[mi][ni][r] + Bc[g];
          if (g < 18)       homT[px * 27 + g] = v;
          else if (g < 27)  homT[px * 27 + g] = fast_sigmoid(v);
        }
      }
    }
  }

  // sampler per-pixel identity: 4 thr/px x 16 ch
  const int cq = t >> 6, pxl = t & 63, c0 = cq << 4;
  const int ww = w0 + pxl;
  const ushort* xb = xtb + ((size_t)b << 20);

  f32x4 aco[2][2];
  #pragma unroll
  for (int mi = 0; mi < 2; mi++)
    #pragma unroll
    for (int ni = 0; ni < 2; ni++) aco[mi][ni] = (f32x4){0.f, 0.f, 0.f, 0.f};

  #pragma unroll 1
  for (int k = 0; k < 9; k++) {
    // ---- col GEMM for this k: permuted rows 64+k*64 .. 128+k*64 ----
    const int q = 1 + k, og = q >> 1, ocq = q & 1;
    f32x4 acc[2][2];
    #pragma unroll
    for (int mi = 0; mi < 2; mi++)
      #pragma unroll
      for (int ni = 0; ni < 2; ni++) acc[mi][ni] = (f32x4){0.f, 0.f, 0.f, 0.f};
    __builtin_amdgcn_s_setprio(1);
    #pragma unroll 2
    for (int ks = 0; ks < 18; ks++) {
      const int kk = ks >> 1, half = ks & 1;
      const int dr = kk / 3, dc = kk - dr * 3;
      const ushort* wp8 = Wpk + ((size_t)((((og * 18 + ks) << 1) + ocq) << 11)) + (lane << 3);
      s16x8 af[2], bfr[2];
      #pragma unroll
      for (int mi = 0; mi < 2; mi++)
        af[mi] = *(const s16x8*)(wp8 + (((rowq << 1) + mi) << 9));
      const int gci = half * 4 + kb;
      #pragma unroll
      for (int ni = 0; ni < 2; ni++) {
        int r = (pxq << 5) + ni * 16 + nif;
        int w1 = r + dc;
        int slot = (gci + w1) & 7;
        bfr[ni] = *(const s16x8*)(sF + ((dr * 66 + w1) << 6) + slot * 8);
      }
      #pragma unroll
      for (int mi = 0; mi < 2; mi++)
        #pragma unroll
        for (int ni = 0; ni < 2; ni++)
          acc[mi][ni] = __builtin_amdgcn_mfma_f32_16x16x32_bf16(af[mi], bfr[ni], acc[mi][ni], 0, 0, 0);
    }
    __builtin_amdgcn_s_setprio(0);
    __syncthreads();   // prior k's finalMFMA reads of colT complete (k=0: homT visible)

    // epilogue: tanh -> colT (slot-rotated)
    #pragma unroll
    for (int mi = 0; mi < 2; mi++) {
      #pragma unroll
      for (int ni = 0; ni < 2; ni++) {
        int px = (pxq << 5) + ni * 16 + nif;
        int c = (rowq << 5) + mi * 16 + (quad << 2);
        float4 b4 = *(const float4*)(Bc + 64 + (k << 6) + c);
        ushort v4[4];
        v4[0] = f2bf(fast_tanh(acc[mi][ni][0] + b4.x));
        v4[1] = f2bf(fast_tanh(acc[mi][ni][1] + b4.y));
        v4[2] = f2bf(fast_tanh(acc[mi][ni][2] + b4.z));
        v4[3] = f2bf(fast_tanh(acc[mi][ni][3] + b4.w));
        int slot = ((c >> 3) + px) & 7;
        *(uint2*)(colT + (px << 6) + slot * 8 + (c & 7)) = *(uint2*)v4;
      }
    }
    __syncthreads();   // colT visible to sampler

    // ---- sampler: 16 channels of pixel pxl, in-place update of colT ----
    {
      float ox = homT[pxl * 27 + k];
      float oy = homT[pxl * 27 + 9 + k];
      float mk = homT[pxl * 27 + 18 + k];
      float px_ = (float)(h + k / 3) + ox;
      float py_ = (float)(ww + k % 3) + oy;
      float fx = floorf(px_), fy = floorf(py_);
      float qltx = fminf(fmaxf(fx, 0.f), 129.f);
      float qlty = fminf(fmaxf(fy, 0.f), 129.f);
      float qrbx = fminf(fmaxf(fx + 1.f, 0.f), 129.f);
      float qrby = fminf(fmaxf(fy + 1.f, 0.f), 129.f);
      float sx = fminf(fmaxf(px_, 0.f), 129.f);
      float sy = fminf(fmaxf(py_, 0.f), 129.f);
      float ax = 1.f + qltx - sx, bx = 1.f - qrbx + sx;
      float ay = 1.f + qlty - sy, by = 1.f - qrby + sy;
      int iltx = (int)qltx, ilty = (int)qlty, irbx = (int)qrbx, irby = (int)qrby;
      bool vltx = (iltx >= 1) && (iltx <= 128);
      bool vlty = (ilty >= 1) && (ilty <= 128);
      bool vrbx = (irbx >= 1) && (irbx <= 128);
      bool vrby = (irby >= 1) && (irby <= 128);
      float wl[4];
      int   ofs[4];
      wl[0] = (vltx && vlty) ? ax * ay : 0.f;
      wl[1] = (vrbx && vrby) ? bx * by : 0.f;
      wl[2] = (vltx && vrby) ? ax * by : 0.f;
      wl[3] = (vrbx && vlty) ? bx * ay : 0.f;
      ofs[0] = (vltx && vlty) ? ((iltx - 1) << 7) + (ilty - 1) : 0;
      ofs[1] = (vrbx && vrby) ? ((irbx - 1) << 7) + (irby - 1) : 0;
      ofs[2] = (vltx && vrby) ? ((iltx - 1) << 7) + (irby - 1) : 0;
      ofs[3] = (vrbx && vlty) ? ((irbx - 1) << 7) + (ilty - 1) : 0;

      float pos[16];
      #pragma unroll
      for (int j = 0; j < 16; j++) pos[j] = 0.f;
      #pragma unroll
      for (int corner = 0; corner < 4; corner++) {
        const ushort* p = xb + ((size_t)ofs[corner] << 6) + c0;
        float wgt = wl[corner];
        ushort tmp[16];
        *(uint4*)(tmp)     = *(const uint4*)(p);
        *(uint4*)(tmp + 8) = *(const uint4*)(p + 8);
        #pragma unroll
        for (int j = 0; j < 16; j++) pos[j] += wgt * bf2f(tmp[j]);
      }
      // read own col slots, update, write back (thread-exclusive -> no barrier)
      #pragma unroll
      for (int q2 = 0; q2 < 2; q2++) {
        int chunk = (cq << 1) + q2;
        int slot = (chunk + pxl) & 7;
        ushort* cp = colT + (pxl << 6) + slot * 8;
        ushort ct[8];
        *(uint4*)ct = *(const uint4*)cp;
        #pragma unroll
        for (int j = 0; j < 8; j++)
          ct[j] = f2bf((bf2f(ct[j]) + pos[q2 * 8 + j]) * mk);
        *(uint4*)cp = *(uint4*)ct;
      }
    }
    __syncthreads();   // updated colT visible to MFMA

    // ---- final-GEMM MFMA: 2 ks-steps over this k-tile ----
    __builtin_amdgcn_s_setprio(1);
    #pragma unroll
    for (int khalf = 0; khalf < 2; khalf++) {
      int ks2 = (k << 1) + khalf;
      s16x8 af[2], bfr[2];
      #pragma unroll
      for (int mi = 0; mi < 2; mi++)
        af[mi] = *(const s16x8*)(W2pk + ((((ks2 << 2) + (rowq << 1) + mi) << 6) + lane) * 8);
      const int g0 = (khalf << 2) + kb;
      #pragma unroll
      for (int ni = 0; ni < 2; ni++) {
        int r = (pxq << 5) + ni * 16 + nif;
        int slot = (g0 + r) & 7;
        bfr[ni] = *(const s16x8*)(colT + (r << 6) + slot * 8);
      }
      #pragma unroll
      for (int mi = 0; mi < 2; mi++)
        #pragma unroll
        for (int ni = 0; ni < 2; ni++)
          aco[mi][ni] = __builtin_amdgcn_mfma_f32_16x16x32_bf16(af[mi], bfr[ni], aco[mi][ni], 0, 0, 0);
    }
    __builtin_amdgcn_s_setprio(0);
  }

  // ---- store out ----
  #pragma unroll
  for (int mi = 0; mi < 2; mi++) {
    #pragma unroll
    for (int ni = 0; ni < 2; ni++) {
      int hwp = hw0 + (pxq << 5) + ni * 16 + nif;
      #pragma unroll
      for (int r = 0; r < 4; r++) {
        int o = (rowq << 5) + mi * 16 + (quad << 2) + r;
        out[(((size_t)b * 64 + o) << 14) + hwp] = aco[mi][ni][r];
      }
    }
  }
}

extern "C" void kernel_launch(void* const* d_in, const int* in_sizes, int n_in,
                              void* d_out, int out_size, void* d_ws, size_t ws_size,
                              hipStream_t stream) {
  const float* x     = (const float*)d_in[0];
  const float* ref   = (const float*)d_in[1];
  const float* wcd   = (const float*)d_in[2];
  const float* bcd   = (const float*)d_in[3];
  const float* wp    = (const float*)d_in[4];
  const float* bp    = (const float*)d_in[5];
  const float* wm    = (const float*)d_in[6];
  const float* bm    = (const float*)d_in[7];
  const float* wc    = (const float*)d_in[8];
  const float* bc    = (const float*)d_in[9];
  const float* wconv = (const float*)d_in[10];
  float* out = (float*)d_out;

  char* w8 = (char*)d_ws;
  ushort* Wpk     = (ushort*)(w8 + 0);           //    737,280 B
  float*  Bc      = (float*)(w8 + 737280);       //      2,560 B
  ushort* W2pk    = (ushort*)(w8 + 739840);      //     73,728 B
  ushort* fusedt  = (ushort*)(w8 + 813568);      //  8,388,608 B (pixel-major)
  ushort* xtb     = (ushort*)(w8 + 9202176);     //  8,388,608 B -> total 17,590,784 B

  // blocks [0,1024): fused conv (MFMA) + xtb; blocks [1024,2464): weight packing
  k_fused <<<2464, 256, 0, stream>>>(x, ref, wcd, bcd, wp, bp, wm, bm, wc, bc, wconv,
                                     fusedt, xtb, Wpk, Bc, W2pk);
  k_all   <<<1024, 256, 0, stream>>>(Wpk, fusedt, Bc, xtb, W2pk, out);
}

// Round 12
// 197.520 us; speedup vs baseline: 1.1984x; 1.0033x over previous
//
#include <hip/hip_runtime.h>
#include <hip/hip_bf16.h>
#include <math.h>

typedef short s16x8 __attribute__((ext_vector_type(8)));
typedef float f32x4 __attribute__((ext_vector_type(4)));

__device__ inline ushort f2bf(float f) {
  unsigned u = __float_as_uint(f);
  u = (u + 0x7FFF + ((u >> 16) & 1)) >> 16;
  return (ushort)u;
}
__device__ inline float bf2f(ushort u) {
  return __uint_as_float(((unsigned)u) << 16);
}
// packed f32x2 -> bf16x2 RNE (bit-identical to f2bf pair)
__device__ inline unsigned pkbf(float a, float b) {
  __hip_bfloat162 h = __float22bfloat162_rn(make_float2(a, b));
  return *(unsigned*)&h;
}
// fast activations: v_exp_f32 + v_rcp_f32; saturate correctly at +/-inf.
__device__ inline float fast_tanh(float v) {
  float e = __builtin_amdgcn_exp2f(v * 2.8853900817779268f);   // exp(2v)
  return 1.f - 2.f * __builtin_amdgcn_rcpf(e + 1.f);
}
__device__ inline float fast_sigmoid(float v) {
  float e = __builtin_amdgcn_exp2f(v * -1.4426950408889634f);  // exp(-v)
  return __builtin_amdgcn_rcpf(1.f + e);
}

// ---- PERMUTED head-row space (640 rows):
//   g in [0,18): off | [18,27): mod | [27,64): pad | [64,640): col j=g-64=k*64+c
//     source col channel cc = c*9+k.
// ---- K1: fused 1x1 conv as MFMA GEMM -> fusedt[pix][64] bf16 + xtb, grid 1024.
// Round-12: (1) pack work folded into conv blocks (grid-strided tail) -- removes the
// serialized 1440-block tail; (2) DIRECT-LOAD B-build: chunk g is wave-uniform and
// lane==px, so the 8 x[ci][hw0+px] loads are coalesced 256B wave-reads; fp32 sxf
// staging + 2 barriers deleted. LDS 16,640 B + launch_bounds(256,8) -> 8 blocks/CU,
// VGPR capped at 64. xtb written in a separate coalesced pass (128B rows) from xt_lds.
__global__ __launch_bounds__(256, 8) void k_fused(
    const float* __restrict__ x, const float* __restrict__ ref,
    const float* __restrict__ wcd, const float* __restrict__ bcd,
    const float* __restrict__ wp, const float* __restrict__ bp,
    const float* __restrict__ wm, const float* __restrict__ bm,
    const float* __restrict__ wc, const float* __restrict__ bc,
    const float* __restrict__ wconv,
    ushort* __restrict__ fusedt, ushort* __restrict__ xtb,
    ushort* __restrict__ Wpk, float* __restrict__ Bc, ushort* __restrict__ W2pk) {
  __shared__ __align__(16) ushort xt_lds[64 * 128];   // 16,384 B  B: [px][16 chunks]
  __shared__ float sb[64];                            // -> 16,640 B total

  const int t = threadIdx.x;
  const int b = blockIdx.x >> 8, hw0 = (blockIdx.x & 255) << 6;
  if (t < 64) sb[t] = bcd[t];

  // ---- B-build: direct coalesced global loads, pkbf in regs, rotated LDS write ----
  // wave-uniform g (= waveid + rep*4), lane == px.
  #pragma unroll
  for (int rep = 0; rep < 2; rep++) {
    const int px = t & 63;
    const int g = (t >> 6) + (rep << 2);       // x-chunk 0..7; ref-chunk g+8
    const float* xrow = x   + ((size_t)((b << 6) + (g << 3)) << 14) + hw0 + px;
    const float* rrow = ref + ((size_t)((b << 6) + (g << 3)) << 14) + hw0 + px;
    float v[8];
    #pragma unroll
    for (int e = 0; e < 8; e++) v[e] = xrow[(size_t)e << 14];
    uint4 ow;
    ow.x = pkbf(v[0], v[1]); ow.y = pkbf(v[2], v[3]);
    ow.z = pkbf(v[4], v[5]); ow.w = pkbf(v[6], v[7]);
    *(uint4*)(xt_lds + px * 128 + (((g + px) & 15) << 3)) = ow;
    #pragma unroll
    for (int e = 0; e < 8; e++) v[e] = rrow[(size_t)e << 14];
    uint4 orf;
    orf.x = pkbf(v[0], v[1]); orf.y = pkbf(v[2], v[3]);
    orf.z = pkbf(v[4], v[5]); orf.w = pkbf(v[6], v[7]);
    *(uint4*)(xt_lds + px * 128 + (((g + 8 + px) & 15) << 3)) = orf;
  }
  __syncthreads();

  // ---- coalesced xtb writer: 4 lanes cover one 128B row (x-half chunks 0..7) ----
  {
    const int px = t >> 2, j0 = (t & 3) << 1;   // row, chunks {j0, j0+1}
    const ushort* rowp = xt_lds + px * 128;
    uint4 c0 = *(const uint4*)(rowp + (((j0 + px) & 15) << 3));
    uint4 c1 = *(const uint4*)(rowp + (((j0 + 1 + px) & 15) << 3));
    ushort* dst = xtb + (((size_t)b << 14) + hw0 + px) * 64 + (j0 << 3);
    *(uint4*)dst       = c0;
    *(uint4*)(dst + 8) = c1;
  }

  // ---- GEMM: wave -> 16 oc, 4 ni x 4 ksteps MFMAs; A-fragments from global (L2) ----
  const int lane = t & 63, wv4 = t >> 6;
  const int ocl = lane & 15, kb = lane >> 4;
  const int ocr = (wv4 << 4) + ocl;
  f32x4 acc[4];
  #pragma unroll
  for (int ni = 0; ni < 4; ni++) acc[ni] = (f32x4){0.f, 0.f, 0.f, 0.f};
  #pragma unroll
  for (int s = 0; s < 4; s++) {
    const int gA = (s << 2) + kb;
    const float4* wr4 = (const float4*)(wcd + ocr * 128 + (gA << 3));
    float4 wa = wr4[0], wb2 = wr4[1];
    unsigned aw[4];
    aw[0] = pkbf(wa.x, wa.y);   aw[1] = pkbf(wa.z, wa.w);
    aw[2] = pkbf(wb2.x, wb2.y); aw[3] = pkbf(wb2.z, wb2.w);
    s16x8 af = *(const s16x8*)aw;
    #pragma unroll
    for (int ni = 0; ni < 4; ni++) {
      const int px = (ni << 4) + ocl;
      s16x8 bf8 = *(const s16x8*)(xt_lds + px * 128 + (((gA + px) & 15) << 3));
      acc[ni] = __builtin_amdgcn_mfma_f32_16x16x32_bf16(af, bf8, acc[ni], 0, 0, 0);
    }
  }
  // epilogue: +bias, pack bf16, store fusedt[pix][oc]
  const float4 b4 = *(const float4*)&sb[(wv4 << 4) + (kb << 2)];
  #pragma unroll
  for (int ni = 0; ni < 4; ni++) {
    const int px = (ni << 4) + ocl;
    uint2 o;
    o.x = pkbf(acc[ni][0] + b4.x, acc[ni][1] + b4.y);
    o.y = pkbf(acc[ni][2] + b4.z, acc[ni][3] + b4.w);
    *(uint2*)(fusedt + (((size_t)(b << 14) + hw0 + px) << 6) + (wv4 << 4) + (kb << 2)) = o;
  }

  // ---- weight packing (former pack blocks), grid-strided over 262,144 threads ----
  const int gid = blockIdx.x * 256 + t;
  for (int i = gid; i < 368640; i += 262144) {
    int e = i & 7, lne = (i >> 3) & 63, mi = (i >> 9) & 3, ocq = (i >> 11) & 1;
    int hi = i >> 12;                 // 0..89
    int ks = hi % 18, og = hi / 18;
    int g = og * 128 + ocq * 64 + mi * 16 + (lne & 15);
    int ci = ((ks & 1) << 5) + ((lne >> 4) << 3) + e;
    int kk = ks >> 1;
    int col = ci * 9 + kk;
    float v = 0.f;
    if (g < 18)       v = wp[g * 576 + col];
    else if (g < 27)  v = wm[(g - 18) * 576 + col];
    else if (g >= 64) {
      int j = g - 64;
      int cc = (j & 63) * 9 + (j >> 6);
      v = wc[cc * 576 + col];
    }
    Wpk[i] = f2bf(v);
  }
  if (gid < 36864) {
    int e = gid & 7, lne = (gid >> 3) & 63, mi = (gid >> 9) & 3, ks = gid >> 11;  // 0..17
    int o = mi * 16 + (lne & 15);
    int p = (ks << 5) + ((lne >> 4) << 3) + e;
    int kk2 = p >> 6, c = p & 63;
    W2pk[gid] = f2bf(wconv[o * 576 + c * 9 + kk2]);
  }
  if (gid < 640) {
    float bv = 0.f;
    if (gid < 18)       bv = bp[gid];
    else if (gid < 27)  bv = bm[gid - 18];
    else if (gid >= 64) {
      int j = gid - 64;
      bv = bc[(j & 63) * 9 + (j >> 6)];
    }
    Bc[gid] = bv;
  }
}

// ---- K3: FULLY FUSED head-GEMM + sampler + final GEMM, 64-px tiles --------------------
// BYTE-EXACT round-11 version (111.4 us, VGPR 64 -- the <=64-VGPR recompute-heavy
// regime is load-bearing; round-9's +4 VGPR cost 27 us). setprio around MFMA clusters.
// grid 1024; block 256 = 4 waves; 4 blocks/CU (LDS 40,448B).
__global__ __launch_bounds__(256) void k_all(
    const ushort* __restrict__ Wpk, const ushort* __restrict__ fusedt,
    const float* __restrict__ Bc, const ushort* __restrict__ xtb,
    const ushort* __restrict__ W2pk, float* __restrict__ out) {
  __shared__ __align__(16) ushort sF[3 * 66 * 64];    // 25,344 B
  __shared__ __align__(16) ushort colT[64 * 64];      //  8,192 B
  __shared__ float homT[64 * 27];                     //  6,912 B
  const int t = threadIdx.x;
  const int lane = t & 63, wv = t >> 6;
  const int rowid = blockIdx.x;           // b*256 + h*2 + half
  const int b = rowid >> 8;
  const int rem = rowid & 255;
  const int h = rem >> 1, hf = rem & 1;
  const int w0 = hf << 6;
  const int hw0 = (h << 7) + w0;

  // stage fused rows h-1..h+1, w1 in [0,66) covering gw in [w0-1, w0+64]
  for (int idx = t; idx < 1584; idx += 256) {   // 198 pixels x 8 ci-chunks
    int p = idx >> 3, j = idx & 7;
    int row = p / 66, w1 = p - row * 66;
    int gh = h + row - 1, gw = w0 + w1 - 1;
    uint4 v = make_uint4(0u, 0u, 0u, 0u);
    if (gh >= 0 && gh < 128 && (unsigned)gw < 128u)
      v = *(const uint4*)(fusedt + ((size_t)((b << 14) + (gh << 7) + gw) << 6) + j * 8);
    int slot = (j + w1) & 7;
    *(uint4*)(sF + (p << 6) + slot * 8) = v;
  }
  __syncthreads();

  const int pxq = wv & 1, rowq = wv >> 1;
  const int nif = lane & 15, kb = lane >> 4, quad = lane >> 4;

  // ---- off/mod GEMM: permuted rows 0..31 (rowq==0 waves only) ----
  if (rowq == 0) {
    f32x4 acc[2][2];
    #pragma unroll
    for (int mi = 0; mi < 2; mi++)
      #pragma unroll
      for (int ni = 0; ni < 2; ni++) acc[mi][ni] = (f32x4){0.f, 0.f, 0.f, 0.f};
    __builtin_amdgcn_s_setprio(1);
    #pragma unroll 2
    for (int ks = 0; ks < 18; ks++) {
      const int kk = ks >> 1, half = ks & 1;
      const int dr = kk / 3, dc = kk - dr * 3;
      const ushort* wp8 = Wpk + ((size_t)(ks << 12)) + (lane << 3);  // og=0, ocq=0
      s16x8 af[2], bfr[2];
      #pragma unroll
      for (int mi = 0; mi < 2; mi++)
        af[mi] = *(const s16x8*)(wp8 + (mi << 9));
      const int gci = half * 4 + kb;
      #pragma unroll
      for (int ni = 0; ni < 2; ni++) {
        int r = (pxq << 5) + ni * 16 + nif;
        int w1 = r + dc;
        int slot = (gci + w1) & 7;
        bfr[ni] = *(const s16x8*)(sF + ((dr * 66 + w1) << 6) + slot * 8);
      }
      #pragma unroll
      for (int mi = 0; mi < 2; mi++)
        #pragma unroll
        for (int ni = 0; ni < 2; ni++)
          acc[mi][ni] = __builtin_amdgcn_mfma_f32_16x16x32_bf16(af[mi], bfr[ni], acc[mi][ni], 0, 0, 0);
    }
    __builtin_amdgcn_s_setprio(0);
    #pragma unroll
    for (int mi = 0; mi < 2; mi++) {
      #pragma unroll
      for (int ni = 0; ni < 2; ni++) {
        int px = (pxq << 5) + ni * 16 + nif;
        #pragma unroll
        for (int r = 0; r < 4; r++) {
          int g = mi * 16 + (quad << 2) + r;
          float v = acc[mi][ni][r] + Bc[g];
          if (g < 18)       homT[px * 27 + g] = v;
          else if (g < 27)  homT[px * 27 + g] = fast_sigmoid(v);
        }
      }
    }
  }

  // sampler per-pixel identity: 4 thr/px x 16 ch
  const int cq = t >> 6, pxl = t & 63, c0 = cq << 4;
  const int ww = w0 + pxl;
  const ushort* xb = xtb + ((size_t)b << 20);

  f32x4 aco[2][2];
  #pragma unroll
  for (int mi = 0; mi < 2; mi++)
    #pragma unroll
    for (int ni = 0; ni < 2; ni++) aco[mi][ni] = (f32x4){0.f, 0.f, 0.f, 0.f};

  #pragma unroll 1
  for (int k = 0; k < 9; k++) {
    // ---- col GEMM for this k: permuted rows 64+k*64 .. 128+k*64 ----
    const int q = 1 + k, og = q >> 1, ocq = q & 1;
    f32x4 acc[2][2];
    #pragma unroll
    for (int mi = 0; mi < 2; mi++)
      #pragma unroll
      for (int ni = 0; ni < 2; ni++) acc[mi][ni] = (f32x4){0.f, 0.f, 0.f, 0.f};
    __builtin_amdgcn_s_setprio(1);
    #pragma unroll 2
    for (int ks = 0; ks < 18; ks++) {
      const int kk = ks >> 1, half = ks & 1;
      const int dr = kk / 3, dc = kk - dr * 3;
      const ushort* wp8 = Wpk + ((size_t)((((og * 18 + ks) << 1) + ocq) << 11)) + (lane << 3);
      s16x8 af[2], bfr[2];
      #pragma unroll
      for (int mi = 0; mi < 2; mi++)
        af[mi] = *(const s16x8*)(wp8 + (((rowq << 1) + mi) << 9));
      const int gci = half * 4 + kb;
      #pragma unroll
      for (int ni = 0; ni < 2; ni++) {
        int r = (pxq << 5) + ni * 16 + nif;
        int w1 = r + dc;
        int slot = (gci + w1) & 7;
        bfr[ni] = *(const s16x8*)(sF + ((dr * 66 + w1) << 6) + slot * 8);
      }
      #pragma unroll
      for (int mi = 0; mi < 2; mi++)
        #pragma unroll
        for (int ni = 0; ni < 2; ni++)
          acc[mi][ni] = __builtin_amdgcn_mfma_f32_16x16x32_bf16(af[mi], bfr[ni], acc[mi][ni], 0, 0, 0);
    }
    __builtin_amdgcn_s_setprio(0);
    __syncthreads();   // prior k's finalMFMA reads of colT complete (k=0: homT visible)

    // epilogue: tanh -> colT (slot-rotated)
    #pragma unroll
    for (int mi = 0; mi < 2; mi++) {
      #pragma unroll
      for (int ni = 0; ni < 2; ni++) {
        int px = (pxq << 5) + ni * 16 + nif;
        int c = (rowq << 5) + mi * 16 + (quad << 2);
        float4 b4 = *(const float4*)(Bc + 64 + (k << 6) + c);
        ushort v4[4];
        v4[0] = f2bf(fast_tanh(acc[mi][ni][0] + b4.x));
        v4[1] = f2bf(fast_tanh(acc[mi][ni][1] + b4.y));
        v4[2] = f2bf(fast_tanh(acc[mi][ni][2] + b4.z));
        v4[3] = f2bf(fast_tanh(acc[mi][ni][3] + b4.w));
        int slot = ((c >> 3) + px) & 7;
        *(uint2*)(colT + (px << 6) + slot * 8 + (c & 7)) = *(uint2*)v4;
      }
    }
    __syncthreads();   // colT visible to sampler

    // ---- sampler: 16 channels of pixel pxl, in-place update of colT ----
    {
      float ox = homT[pxl * 27 + k];
      float oy = homT[pxl * 27 + 9 + k];
      float mk = homT[pxl * 27 + 18 + k];
      float px_ = (float)(h + k / 3) + ox;
      float py_ = (float)(ww + k % 3) + oy;
      float fx = floorf(px_), fy = floorf(py_);
      float qltx = fminf(fmaxf(fx, 0.f), 129.f);
      float qlty = fminf(fmaxf(fy, 0.f), 129.f);
      float qrbx = fminf(fmaxf(fx + 1.f, 0.f), 129.f);
      float qrby = fminf(fmaxf(fy + 1.f, 0.f), 129.f);
      float sx = fminf(fmaxf(px_, 0.f), 129.f);
      float sy = fminf(fmaxf(py_, 0.f), 129.f);
      float ax = 1.f + qltx - sx, bx = 1.f - qrbx + sx;
      float ay = 1.f + qlty - sy, by = 1.f - qrby + sy;
      int iltx = (int)qltx, ilty = (int)qlty, irbx = (int)qrbx, irby = (int)qrby;
      bool vltx = (iltx >= 1) && (iltx <= 128);
      bool vlty = (ilty >= 1) && (ilty <= 128);
      bool vrbx = (irbx >= 1) && (irbx <= 128);
      bool vrby = (irby >= 1) && (irby <= 128);
      float wl[4];
      int   ofs[4];
      wl[0] = (vltx && vlty) ? ax * ay : 0.f;
      wl[1] = (vrbx && vrby) ? bx * by : 0.f;
      wl[2] = (vltx && vrby) ? ax * by : 0.f;
      wl[3] = (vrbx && vlty) ? bx * ay : 0.f;
      ofs[0] = (vltx && vlty) ? ((iltx - 1) << 7) + (ilty - 1) : 0;
      ofs[1] = (vrbx && vrby) ? ((irbx - 1) << 7) + (irby - 1) : 0;
      ofs[2] = (vltx && vrby) ? ((iltx - 1) << 7) + (irby - 1) : 0;
      ofs[3] = (vrbx && vlty) ? ((irbx - 1) << 7) + (ilty - 1) : 0;

      float pos[16];
      #pragma unroll
      for (int j = 0; j < 16; j++) pos[j] = 0.f;
      #pragma unroll
      for (int corner = 0; corner < 4; corner++) {
        const ushort* p = xb + ((size_t)ofs[corner] << 6) + c0;
        float wgt = wl[corner];
        ushort tmp[16];
        *(uint4*)(tmp)     = *(const uint4*)(p);
        *(uint4*)(tmp + 8) = *(const uint4*)(p + 8);
        #pragma unroll
        for (int j = 0; j < 16; j++) pos[j] += wgt * bf2f(tmp[j]);
      }
      // read own col slots, update, write back (thread-exclusive -> no barrier)
      #pragma unroll
      for (int q2 = 0; q2 < 2; q2++) {
        int chunk = (cq << 1) + q2;
        int slot = (chunk + pxl) & 7;
        ushort* cp = colT + (pxl << 6) + slot * 8;
        ushort ct[8];
        *(uint4*)ct = *(const uint4*)cp;
        #pragma unroll
        for (int j = 0; j < 8; j++)
          ct[j] = f2bf((bf2f(ct[j]) + pos[q2 * 8 + j]) * mk);
        *(uint4*)cp = *(uint4*)ct;
      }
    }
    __syncthreads();   // updated colT visible to MFMA

    // ---- final-GEMM MFMA: 2 ks-steps over this k-tile ----
    __builtin_amdgcn_s_setprio(1);
    #pragma unroll
    for (int khalf = 0; khalf < 2; khalf++) {
      int ks2 = (k << 1) + khalf;
      s16x8 af[2], bfr[2];
      #pragma unroll
      for (int mi = 0; mi < 2; mi++)
        af[mi] = *(const s16x8*)(W2pk + ((((ks2 << 2) + (rowq << 1) + mi) << 6) + lane) * 8);
      const int g0 = (khalf << 2) + kb;
      #pragma unroll
      for (int ni = 0; ni < 2; ni++) {
        int r = (pxq << 5) + ni * 16 + nif;
        int slot = (g0 + r) & 7;
        bfr[ni] = *(const s16x8*)(colT + (r << 6) + slot * 8);
      }
      #pragma unroll
      for (int mi = 0; mi < 2; mi++)
        #pragma unroll
        for (int ni = 0; ni < 2; ni++)
          aco[mi][ni] = __builtin_amdgcn_mfma_f32_16x16x32_bf16(af[mi], bfr[ni], aco[mi][ni], 0, 0, 0);
    }
    __builtin_amdgcn_s_setprio(0);
  }

  // ---- store out ----
  #pragma unroll
  for (int mi = 0; mi < 2; mi++) {
    #pragma unroll
    for (int ni = 0; ni < 2; ni++) {
      int hwp = hw0 + (pxq << 5) + ni * 16 + nif;
      #pragma unroll
      for (int r = 0; r < 4; r++) {
        int o = (rowq << 5) + mi * 16 + (quad << 2) + r;
        out[(((size_t)b * 64 + o) << 14) + hwp] = aco[mi][ni][r];
      }
    }
  }
}

extern "C" void kernel_launch(void* const* d_in, const int* in_sizes, int n_in,
                              void* d_out, int out_size, void* d_ws, size_t ws_size,
                              hipStream_t stream) {
  const float* x     = (const float*)d_in[0];
  const float* ref   = (const float*)d_in[1];
  const float* wcd   = (const float*)d_in[2];
  const float* bcd   = (const float*)d_in[3];
  const float* wp    = (const float*)d_in[4];
  const float* bp    = (const float*)d_in[5];
  const float* wm    = (const float*)d_in[6];
  const float* bm    = (const float*)d_in[7];
  const float* wc    = (const float*)d_in[8];
  const float* bc    = (const float*)d_in[9];
  const float* wconv = (const float*)d_in[10];
  float* out = (float*)d_out;

  char* w8 = (char*)d_ws;
  ushort* Wpk     = (ushort*)(w8 + 0);           //    737,280 B
  float*  Bc      = (float*)(w8 + 737280);       //      2,560 B
  ushort* W2pk    = (ushort*)(w8 + 739840);      //     73,728 B
  ushort* fusedt  = (ushort*)(w8 + 813568);      //  8,388,608 B (pixel-major)
  ushort* xtb     = (ushort*)(w8 + 9202176);     //  8,388,608 B -> total 17,590,784 B

  k_fused <<<1024, 256, 0, stream>>>(x, ref, wcd, bcd, wp, bp, wm, bm, wc, bc, wconv,
                                     fusedt, xtb, Wpk, Bc, W2pk);
  k_all   <<<1024, 256, 0, stream>>>(Wpk, fusedt, Bc, xtb, W2pk, out);
}

// Round 13
// 196.079 us; speedup vs baseline: 1.2073x; 1.0073x over previous
//
#include <hip/hip_runtime.h>
#include <hip/hip_bf16.h>
#include <math.h>

typedef short s16x8 __attribute__((ext_vector_type(8)));
typedef float f32x4 __attribute__((ext_vector_type(4)));

__device__ inline ushort f2bf(float f) {
  unsigned u = __float_as_uint(f);
  u = (u + 0x7FFF + ((u >> 16) & 1)) >> 16;
  return (ushort)u;
}
__device__ inline float bf2f(ushort u) {
  return __uint_as_float(((unsigned)u) << 16);
}
// packed f32x2 -> bf16x2 RNE (bit-identical to f2bf pair)
__device__ inline unsigned pkbf(float a, float b) {
  __hip_bfloat162 h = __float22bfloat162_rn(make_float2(a, b));
  return *(unsigned*)&h;
}
// fast activations: v_exp_f32 + v_rcp_f32; saturate correctly at +/-inf.
__device__ inline float fast_tanh(float v) {
  float e = __builtin_amdgcn_exp2f(v * 2.8853900817779268f);   // exp(2v)
  return 1.f - 2.f * __builtin_amdgcn_rcpf(e + 1.f);
}
__device__ inline float fast_sigmoid(float v) {
  float e = __builtin_amdgcn_exp2f(v * -1.4426950408889634f);  // exp(-v)
  return __builtin_amdgcn_rcpf(1.f + e);
}

// ---- PERMUTED head-row space (640 rows):
//   g in [0,18): off | [18,27): mod | [27,64): pad | [64,640): col j=g-64=k*64+c
//     source col channel cc = c*9+k.
// ---- K1: fused 1x1 conv as MFMA GEMM -> fusedt[pix][64] bf16 + xtb, grid 1024.
// Round-13: fusedt store COALESCED via LDS transpose. The old direct store (8B/lane at
// 128B stride, present since round 0) dirtied 64 sectors per instruction (~8x write
// amplification). Now: acc -> xt_lds[px][72-pad] after the GEMM (xt_lds dead, 1 extra
// barrier), then 4 lanes emit one 128B fusedt row fully coalesced.
__global__ __launch_bounds__(256, 8) void k_fused(
    const float* __restrict__ x, const float* __restrict__ ref,
    const float* __restrict__ wcd, const float* __restrict__ bcd,
    const float* __restrict__ wp, const float* __restrict__ bp,
    const float* __restrict__ wm, const float* __restrict__ bm,
    const float* __restrict__ wc, const float* __restrict__ bc,
    const float* __restrict__ wconv,
    ushort* __restrict__ fusedt, ushort* __restrict__ xtb,
    ushort* __restrict__ Wpk, float* __restrict__ Bc, ushort* __restrict__ W2pk) {
  __shared__ __align__(16) ushort xt_lds[64 * 128];   // 16,384 B  B: [px][16 chunks]
  __shared__ float sb[64];                            // -> 16,640 B total

  const int t = threadIdx.x;
  const int b = blockIdx.x >> 8, hw0 = (blockIdx.x & 255) << 6;
  if (t < 64) sb[t] = bcd[t];

  // ---- B-build: direct coalesced global loads, pkbf in regs, rotated LDS write ----
  // wave-uniform g (= waveid + rep*4), lane == px.
  #pragma unroll
  for (int rep = 0; rep < 2; rep++) {
    const int px = t & 63;
    const int g = (t >> 6) + (rep << 2);       // x-chunk 0..7; ref-chunk g+8
    const float* xrow = x   + ((size_t)((b << 6) + (g << 3)) << 14) + hw0 + px;
    const float* rrow = ref + ((size_t)((b << 6) + (g << 3)) << 14) + hw0 + px;
    float v[8];
    #pragma unroll
    for (int e = 0; e < 8; e++) v[e] = xrow[(size_t)e << 14];
    uint4 ow;
    ow.x = pkbf(v[0], v[1]); ow.y = pkbf(v[2], v[3]);
    ow.z = pkbf(v[4], v[5]); ow.w = pkbf(v[6], v[7]);
    *(uint4*)(xt_lds + px * 128 + (((g + px) & 15) << 3)) = ow;
    #pragma unroll
    for (int e = 0; e < 8; e++) v[e] = rrow[(size_t)e << 14];
    uint4 orf;
    orf.x = pkbf(v[0], v[1]); orf.y = pkbf(v[2], v[3]);
    orf.z = pkbf(v[4], v[5]); orf.w = pkbf(v[6], v[7]);
    *(uint4*)(xt_lds + px * 128 + (((g + 8 + px) & 15) << 3)) = orf;
  }
  __syncthreads();

  // ---- coalesced xtb writer: 4 lanes cover one 128B row (x-half chunks 0..7) ----
  {
    const int px = t >> 2, j0 = (t & 3) << 1;   // row, chunks {j0, j0+1}
    const ushort* rowp = xt_lds + px * 128;
    uint4 c0 = *(const uint4*)(rowp + (((j0 + px) & 15) << 3));
    uint4 c1 = *(const uint4*)(rowp + (((j0 + 1 + px) & 15) << 3));
    ushort* dst = xtb + (((size_t)b << 14) + hw0 + px) * 64 + (j0 << 3);
    *(uint4*)dst       = c0;
    *(uint4*)(dst + 8) = c1;
  }

  // ---- GEMM: wave -> 16 oc, 4 ni x 4 ksteps MFMAs; A-fragments from global (L2) ----
  const int lane = t & 63, wv4 = t >> 6;
  const int ocl = lane & 15, kb = lane >> 4;
  const int ocr = (wv4 << 4) + ocl;
  f32x4 acc[4];
  #pragma unroll
  for (int ni = 0; ni < 4; ni++) acc[ni] = (f32x4){0.f, 0.f, 0.f, 0.f};
  #pragma unroll
  for (int s = 0; s < 4; s++) {
    const int gA = (s << 2) + kb;
    const float4* wr4 = (const float4*)(wcd + ocr * 128 + (gA << 3));
    float4 wa = wr4[0], wb2 = wr4[1];
    unsigned aw[4];
    aw[0] = pkbf(wa.x, wa.y);   aw[1] = pkbf(wa.z, wa.w);
    aw[2] = pkbf(wb2.x, wb2.y); aw[3] = pkbf(wb2.z, wb2.w);
    s16x8 af = *(const s16x8*)aw;
    #pragma unroll
    for (int ni = 0; ni < 4; ni++) {
      const int px = (ni << 4) + ocl;
      s16x8 bf8 = *(const s16x8*)(xt_lds + px * 128 + (((gA + px) & 15) << 3));
      acc[ni] = __builtin_amdgcn_mfma_f32_16x16x32_bf16(af, bf8, acc[ni], 0, 0, 0);
    }
  }
  __syncthreads();   // all MFMA reads of xt_lds done -> reuse as fusedt transpose buf

  // ---- fusedt epilogue: +bias, pack, transpose via LDS, coalesced store ----
  // ft[px][72-pad]: 144B row stride (16B-aligned, banks spread). 9,216 B < 16 KB.
  {
    ushort* ft = xt_lds;
    const float4 b4 = *(const float4*)&sb[(wv4 << 4) + (kb << 2)];
    #pragma unroll
    for (int ni = 0; ni < 4; ni++) {
      const int px = (ni << 4) + ocl;
      uint2 o;
      o.x = pkbf(acc[ni][0] + b4.x, acc[ni][1] + b4.y);
      o.y = pkbf(acc[ni][2] + b4.z, acc[ni][3] + b4.w);
      *(uint2*)(ft + px * 72 + (wv4 << 4) + (kb << 2)) = o;
    }
    __syncthreads();
    const int px = t >> 2, c0 = (t & 3) << 4;   // 4 lanes per 128B fusedt row
    uint4 f0 = *(const uint4*)(ft + px * 72 + c0);
    uint4 f1 = *(const uint4*)(ft + px * 72 + c0 + 8);
    ushort* dst = fusedt + (((size_t)(b << 14) + hw0 + px) << 6) + c0;
    *(uint4*)dst       = f0;
    *(uint4*)(dst + 8) = f1;
  }

  // ---- weight packing (former pack blocks), grid-strided over 262,144 threads ----
  const int gid = blockIdx.x * 256 + t;
  for (int i = gid; i < 368640; i += 262144) {
    int e = i & 7, lne = (i >> 3) & 63, mi = (i >> 9) & 3, ocq = (i >> 11) & 1;
    int hi = i >> 12;                 // 0..89
    int ks = hi % 18, og = hi / 18;
    int g = og * 128 + ocq * 64 + mi * 16 + (lne & 15);
    int ci = ((ks & 1) << 5) + ((lne >> 4) << 3) + e;
    int kk = ks >> 1;
    int col = ci * 9 + kk;
    float v = 0.f;
    if (g < 18)       v = wp[g * 576 + col];
    else if (g < 27)  v = wm[(g - 18) * 576 + col];
    else if (g >= 64) {
      int j = g - 64;
      int cc = (j & 63) * 9 + (j >> 6);
      v = wc[cc * 576 + col];
    }
    Wpk[i] = f2bf(v);
  }
  if (gid < 36864) {
    int e = gid & 7, lne = (gid >> 3) & 63, mi = (gid >> 9) & 3, ks = gid >> 11;  // 0..17
    int o = mi * 16 + (lne & 15);
    int p = (ks << 5) + ((lne >> 4) << 3) + e;
    int kk2 = p >> 6, c = p & 63;
    W2pk[gid] = f2bf(wconv[o * 576 + c * 9 + kk2]);
  }
  if (gid < 640) {
    float bv = 0.f;
    if (gid < 18)       bv = bp[gid];
    else if (gid < 27)  bv = bm[gid - 18];
    else if (gid >= 64) {
      int j = gid - 64;
      bv = bc[(j & 63) * 9 + (j >> 6)];
    }
    Bc[gid] = bv;
  }
}

// ---- K3: FULLY FUSED head-GEMM + sampler + final GEMM, 64-px tiles --------------------
// BYTE-EXACT round-11/12 version (111-116 us, VGPR 64 -- the <=64-VGPR recompute-heavy
// regime is load-bearing; round-9's +4 VGPR cost 27 us). setprio around MFMA clusters.
// grid 1024; block 256 = 4 waves; 4 blocks/CU (LDS 40,448B).
__global__ __launch_bounds__(256) void k_all(
    const ushort* __restrict__ Wpk, const ushort* __restrict__ fusedt,
    const float* __restrict__ Bc, const ushort* __restrict__ xtb,
    const ushort* __restrict__ W2pk, float* __restrict__ out) {
  __shared__ __align__(16) ushort sF[3 * 66 * 64];    // 25,344 B
  __shared__ __align__(16) ushort colT[64 * 64];      //  8,192 B
  __shared__ float homT[64 * 27];                     //  6,912 B
  const int t = threadIdx.x;
  const int lane = t & 63, wv = t >> 6;
  const int rowid = blockIdx.x;           // b*256 + h*2 + half
  const int b = rowid >> 8;
  const int rem = rowid & 255;
  const int h = rem >> 1, hf = rem & 1;
  const int w0 = hf << 6;
  const int hw0 = (h << 7) + w0;

  // stage fused rows h-1..h+1, w1 in [0,66) covering gw in [w0-1, w0+64]
  for (int idx = t; idx < 1584; idx += 256) {   // 198 pixels x 8 ci-chunks
    int p = idx >> 3, j = idx & 7;
    int row = p / 66, w1 = p - row * 66;
    int gh = h + row - 1, gw = w0 + w1 - 1;
    uint4 v = make_uint4(0u, 0u, 0u, 0u);
    if (gh >= 0 && gh < 128 && (unsigned)gw < 128u)
      v = *(const uint4*)(fusedt + ((size_t)((b << 14) + (gh << 7) + gw) << 6) + j * 8);
    int slot = (j + w1) & 7;
    *(uint4*)(sF + (p << 6) + slot * 8) = v;
  }
  __syncthreads();

  const int pxq = wv & 1, rowq = wv >> 1;
  const int nif = lane & 15, kb = lane >> 4, quad = lane >> 4;

  // ---- off/mod GEMM: permuted rows 0..31 (rowq==0 waves only) ----
  if (rowq == 0) {
    f32x4 acc[2][2];
    #pragma unroll
    for (int mi = 0; mi < 2; mi++)
      #pragma unroll
      for (int ni = 0; ni < 2; ni++) acc[mi][ni] = (f32x4){0.f, 0.f, 0.f, 0.f};
    __builtin_amdgcn_s_setprio(1);
    #pragma unroll 2
    for (int ks = 0; ks < 18; ks++) {
      const int kk = ks >> 1, half = ks & 1;
      const int dr = kk / 3, dc = kk - dr * 3;
      const ushort* wp8 = Wpk + ((size_t)(ks << 12)) + (lane << 3);  // og=0, ocq=0
      s16x8 af[2], bfr[2];
      #pragma unroll
      for (int mi = 0; mi < 2; mi++)
        af[mi] = *(const s16x8*)(wp8 + (mi << 9));
      const int gci = half * 4 + kb;
      #pragma unroll
      for (int ni = 0; ni < 2; ni++) {
        int r = (pxq << 5) + ni * 16 + nif;
        int w1 = r + dc;
        int slot = (gci + w1) & 7;
        bfr[ni] = *(const s16x8*)(sF + ((dr * 66 + w1) << 6) + slot * 8);
      }
      #pragma unroll
      for (int mi = 0; mi < 2; mi++)
        #pragma unroll
        for (int ni = 0; ni < 2; ni++)
          acc[mi][ni] = __builtin_amdgcn_mfma_f32_16x16x32_bf16(af[mi], bfr[ni], acc[mi][ni], 0, 0, 0);
    }
    __builtin_amdgcn_s_setprio(0);
    #pragma unroll
    for (int mi = 0; mi < 2; mi++) {
      #pragma unroll
      for (int ni = 0; ni < 2; ni++) {
        int px = (pxq << 5) + ni * 16 + nif;
        #pragma unroll
        for (int r = 0; r < 4; r++) {
          int g = mi * 16 + (quad << 2) + r;
          float v = acc[mi][ni][r] + Bc[g];
          if (g < 18)       homT[px * 27 + g] = v;
          else if (g < 27)  homT[px * 27 + g] = fast_sigmoid(v);
        }
      }
    }
  }

  // sampler per-pixel identity: 4 thr/px x 16 ch
  const int cq = t >> 6, pxl = t & 63, c0 = cq << 4;
  const int ww = w0 + pxl;
  const ushort* xb = xtb + ((size_t)b << 20);

  f32x4 aco[2][2];
  #pragma unroll
  for (int mi = 0; mi < 2; mi++)
    #pragma unroll
    for (int ni = 0; ni < 2; ni++) aco[mi][ni] = (f32x4){0.f, 0.f, 0.f, 0.f};

  #pragma unroll 1
  for (int k = 0; k < 9; k++) {
    // ---- col GEMM for this k: permuted rows 64+k*64 .. 128+k*64 ----
    const int q = 1 + k, og = q >> 1, ocq = q & 1;
    f32x4 acc[2][2];
    #pragma unroll
    for (int mi = 0; mi < 2; mi++)
      #pragma unroll
      for (int ni = 0; ni < 2; ni++) acc[mi][ni] = (f32x4){0.f, 0.f, 0.f, 0.f};
    __builtin_amdgcn_s_setprio(1);
    #pragma unroll 2
    for (int ks = 0; ks < 18; ks++) {
      const int kk = ks >> 1, half = ks & 1;
      const int dr = kk / 3, dc = kk - dr * 3;
      const ushort* wp8 = Wpk + ((size_t)((((og * 18 + ks) << 1) + ocq) << 11)) + (lane << 3);
      s16x8 af[2], bfr[2];
      #pragma unroll
      for (int mi = 0; mi < 2; mi++)
        af[mi] = *(const s16x8*)(wp8 + (((rowq << 1) + mi) << 9));
      const int gci = half * 4 + kb;
      #pragma unroll
      for (int ni = 0; ni < 2; ni++) {
        int r = (pxq << 5) + ni * 16 + nif;
        int w1 = r + dc;
        int slot = (gci + w1) & 7;
        bfr[ni] = *(const s16x8*)(sF + ((dr * 66 + w1) << 6) + slot * 8);
      }
      #pragma unroll
      for (int mi = 0; mi < 2; mi++)
        #pragma unroll
        for (int ni = 0; ni < 2; ni++)
          acc[mi][ni] = __builtin_amdgcn_mfma_f32_16x16x32_bf16(af[mi], bfr[ni], acc[mi][ni], 0, 0, 0);
    }
    __builtin_amdgcn_s_setprio(0);
    __syncthreads();   // prior k's finalMFMA reads of colT complete (k=0: homT visible)

    // epilogue: tanh -> colT (slot-rotated)
    #pragma unroll
    for (int mi = 0; mi < 2; mi++) {
      #pragma unroll
      for (int ni = 0; ni < 2; ni++) {
        int px = (pxq << 5) + ni * 16 + nif;
        int c = (rowq << 5) + mi * 16 + (quad << 2);
        float4 b4 = *(const float4*)(Bc + 64 + (k << 6) + c);
        ushort v4[4];
        v4[0] = f2bf(fast_tanh(acc[mi][ni][0] + b4.x));
        v4[1] = f2bf(fast_tanh(acc[mi][ni][1] + b4.y));
        v4[2] = f2bf(fast_tanh(acc[mi][ni][2] + b4.z));
        v4[3] = f2bf(fast_tanh(acc[mi][ni][3] + b4.w));
        int slot = ((c >> 3) + px) & 7;
        *(uint2*)(colT + (px << 6) + slot * 8 + (c & 7)) = *(uint2*)v4;
      }
    }
    __syncthreads();   // colT visible to sampler

    // ---- sampler: 16 channels of pixel pxl, in-place update of colT ----
    {
      float ox = homT[pxl * 27 + k];
      float oy = homT[pxl * 27 + 9 + k];
      float mk = homT[pxl * 27 + 18 + k];
      float px_ = (float)(h + k / 3) + ox;
      float py_ = (float)(ww + k % 3) + oy;
      float fx = floorf(px_), fy = floorf(py_);
      float qltx = fminf(fmaxf(fx, 0.f), 129.f);
      float qlty = fminf(fmaxf(fy, 0.f), 129.f);
      float qrbx = fminf(fmaxf(fx + 1.f, 0.f), 129.f);
      float qrby = fminf(fmaxf(fy + 1.f, 0.f), 129.f);
      float sx = fminf(fmaxf(px_, 0.f), 129.f);
      float sy = fminf(fmaxf(py_, 0.f), 129.f);
      float ax = 1.f + qltx - sx, bx = 1.f - qrbx + sx;
      float ay = 1.f + qlty - sy, by = 1.f - qrby + sy;
      int iltx = (int)qltx, ilty = (int)qlty, irbx = (int)qrbx, irby = (int)qrby;
      bool vltx = (iltx >= 1) && (iltx <= 128);
      bool vlty = (ilty >= 1) && (ilty <= 128);
      bool vrbx = (irbx >= 1) && (irbx <= 128);
      bool vrby = (irby >= 1) && (irby <= 128);
      float wl[4];
      int   ofs[4];
      wl[0] = (vltx && vlty) ? ax * ay : 0.f;
      wl[1] = (vrbx && vrby) ? bx * by : 0.f;
      wl[2] = (vltx && vrby) ? ax * by : 0.f;
      wl[3] = (vrbx && vlty) ? bx * ay : 0.f;
      ofs[0] = (vltx && vlty) ? ((iltx - 1) << 7) + (ilty - 1) : 0;
      ofs[1] = (vrbx && vrby) ? ((irbx - 1) << 7) + (irby - 1) : 0;
      ofs[2] = (vltx && vrby) ? ((iltx - 1) << 7) + (irby - 1) : 0;
      ofs[3] = (vrbx && vlty) ? ((irbx - 1) << 7) + (ilty - 1) : 0;

      float pos[16];
      #pragma unroll
      for (int j = 0; j < 16; j++) pos[j] = 0.f;
      #pragma unroll
      for (int corner = 0; corner < 4; corner++) {
        const ushort* p = xb + ((size_t)ofs[corner] << 6) + c0;
        float wgt = wl[corner];
        ushort tmp[16];
        *(uint4*)(tmp)     = *(const uint4*)(p);
        *(uint4*)(tmp + 8) = *(const uint4*)(p + 8);
        #pragma unroll
        for (int j = 0; j < 16; j++) pos[j] += wgt * bf2f(tmp[j]);
      }
      // read own col slots, update, write back (thread-exclusive -> no barrier)
      #pragma unroll
      for (int q2 = 0; q2 < 2; q2++) {
        int chunk = (cq << 1) + q2;
        int slot = (chunk + pxl) & 7;
        ushort* cp = colT + (pxl << 6) + slot * 8;
        ushort ct[8];
        *(uint4*)ct = *(const uint4*)cp;
        #pragma unroll
        for (int j = 0; j < 8; j++)
          ct[j] = f2bf((bf2f(ct[j]) + pos[q2 * 8 + j]) * mk);
        *(uint4*)cp = *(uint4*)ct;
      }
    }
    __syncthreads();   // updated colT visible to MFMA

    // ---- final-GEMM MFMA: 2 ks-steps over this k-tile ----
    __builtin_amdgcn_s_setprio(1);
    #pragma unroll
    for (int khalf = 0; khalf < 2; khalf++) {
      int ks2 = (k << 1) + khalf;
      s16x8 af[2], bfr[2];
      #pragma unroll
      for (int mi = 0; mi < 2; mi++)
        af[mi] = *(const s16x8*)(W2pk + ((((ks2 << 2) + (rowq << 1) + mi) << 6) + lane) * 8);
      const int g0 = (khalf << 2) + kb;
      #pragma unroll
      for (int ni = 0; ni < 2; ni++) {
        int r = (pxq << 5) + ni * 16 + nif;
        int slot = (g0 + r) & 7;
        bfr[ni] = *(const s16x8*)(colT + (r << 6) + slot * 8);
      }
      #pragma unroll
      for (int mi = 0; mi < 2; mi++)
        #pragma unroll
        for (int ni = 0; ni < 2; ni++)
          aco[mi][ni] = __builtin_amdgcn_mfma_f32_16x16x32_bf16(af[mi], bfr[ni], aco[mi][ni], 0, 0, 0);
    }
    __builtin_amdgcn_s_setprio(0);
  }

  // ---- store out ----
  #pragma unroll
  for (int mi = 0; mi < 2; mi++) {
    #pragma unroll
    for (int ni = 0; ni < 2; ni++) {
      int hwp = hw0 + (pxq << 5) + ni * 16 + nif;
      #pragma unroll
      for (int r = 0; r < 4; r++) {
        int o = (rowq << 5) + mi * 16 + (quad << 2) + r;
        out[(((size_t)b * 64 + o) << 14) + hwp] = aco[mi][ni][r];
      }
    }
  }
}

extern "C" void kernel_launch(void* const* d_in, const int* in_sizes, int n_in,
                              void* d_out, int out_size, void* d_ws, size_t ws_size,
                              hipStream_t stream) {
  const float* x     = (const float*)d_in[0];
  const float* ref   = (const float*)d_in[1];
  const float* wcd   = (const float*)d_in[2];
  const float* bcd   = (const float*)d_in[3];
  const float* wp    = (const float*)d_in[4];
  const float* bp    = (const float*)d_in[5];
  const float* wm    = (const float*)d_in[6];
  const float* bm    = (const float*)d_in[7];
  const float* wc    = (const float*)d_in[8];
  const float* bc    = (const float*)d_in[9];
  const float* wconv = (const float*)d_in[10];
  float* out = (float*)d_out;

  char* w8 = (char*)d_ws;
  ushort* Wpk     = (ushort*)(w8 + 0);           //    737,280 B
  float*  Bc      = (float*)(w8 + 737280);       //      2,560 B
  ushort* W2pk    = (ushort*)(w8 + 739840);      //     73,728 B
  ushort* fusedt  = (ushort*)(w8 + 813568);      //  8,388,608 B (pixel-major)
  ushort* xtb     = (ushort*)(w8 + 9202176);     //  8,388,608 B -> total 17,590,784 B

  k_fused <<<1024, 256, 0, stream>>>(x, ref, wcd, bcd, wp, bp, wm, bm, wc, bc, wconv,
                                     fusedt, xtb, Wpk, Bc, W2pk);
  k_all   <<<1024, 256, 0, stream>>>(Wpk, fusedt, Bc, xtb, W2pk, out);
}

// Round 14
// 193.938 us; speedup vs baseline: 1.2206x; 1.0110x over previous
//
#include <hip/hip_runtime.h>
#include <hip/hip_bf16.h>
#include <math.h>

typedef short s16x8 __attribute__((ext_vector_type(8)));
typedef float f32x4 __attribute__((ext_vector_type(4)));

__device__ inline ushort f2bf(float f) {
  unsigned u = __float_as_uint(f);
  u = (u + 0x7FFF + ((u >> 16) & 1)) >> 16;
  return (ushort)u;
}
__device__ inline float bf2f(ushort u) {
  return __uint_as_float(((unsigned)u) << 16);
}
// packed f32x2 -> bf16x2 RNE (bit-identical to f2bf pair)
__device__ inline unsigned pkbf(float a, float b) {
  __hip_bfloat162 h = __float22bfloat162_rn(make_float2(a, b));
  return *(unsigned*)&h;
}
// fast activations: v_exp_f32 + v_rcp_f32; saturate correctly at +/-inf.
__device__ inline float fast_tanh(float v) {
  float e = __builtin_amdgcn_exp2f(v * 2.8853900817779268f);   // exp(2v)
  return 1.f - 2.f * __builtin_amdgcn_rcpf(e + 1.f);
}
__device__ inline float fast_sigmoid(float v) {
  float e = __builtin_amdgcn_exp2f(v * -1.4426950408889634f);  // exp(-v)
  return __builtin_amdgcn_rcpf(1.f + e);
}

// ---- PERMUTED head-row space (640 rows):
//   g in [0,18): off | [18,27): mod | [27,64): pad | [64,640): col j=g-64=k*64+c
//     source col channel cc = c*9+k.
// ---- K1: fused 1x1 conv as MFMA GEMM -> fusedt[pix][64] bf16 + xtb, grid 1024.
// (byte-identical to round 13: direct-load B-build, coalesced xtb + fusedt stores,
//  grid-strided weight-pack tail, 8 blocks/CU)
__global__ __launch_bounds__(256, 8) void k_fused(
    const float* __restrict__ x, const float* __restrict__ ref,
    const float* __restrict__ wcd, const float* __restrict__ bcd,
    const float* __restrict__ wp, const float* __restrict__ bp,
    const float* __restrict__ wm, const float* __restrict__ bm,
    const float* __restrict__ wc, const float* __restrict__ bc,
    const float* __restrict__ wconv,
    ushort* __restrict__ fusedt, ushort* __restrict__ xtb,
    ushort* __restrict__ Wpk, float* __restrict__ Bc, ushort* __restrict__ W2pk) {
  __shared__ __align__(16) ushort xt_lds[64 * 128];   // 16,384 B  B: [px][16 chunks]
  __shared__ float sb[64];                            // -> 16,640 B total

  const int t = threadIdx.x;
  const int b = blockIdx.x >> 8, hw0 = (blockIdx.x & 255) << 6;
  if (t < 64) sb[t] = bcd[t];

  // ---- B-build: direct coalesced global loads, pkbf in regs, rotated LDS write ----
  #pragma unroll
  for (int rep = 0; rep < 2; rep++) {
    const int px = t & 63;
    const int g = (t >> 6) + (rep << 2);       // x-chunk 0..7; ref-chunk g+8
    const float* xrow = x   + ((size_t)((b << 6) + (g << 3)) << 14) + hw0 + px;
    const float* rrow = ref + ((size_t)((b << 6) + (g << 3)) << 14) + hw0 + px;
    float v[8];
    #pragma unroll
    for (int e = 0; e < 8; e++) v[e] = xrow[(size_t)e << 14];
    uint4 ow;
    ow.x = pkbf(v[0], v[1]); ow.y = pkbf(v[2], v[3]);
    ow.z = pkbf(v[4], v[5]); ow.w = pkbf(v[6], v[7]);
    *(uint4*)(xt_lds + px * 128 + (((g + px) & 15) << 3)) = ow;
    #pragma unroll
    for (int e = 0; e < 8; e++) v[e] = rrow[(size_t)e << 14];
    uint4 orf;
    orf.x = pkbf(v[0], v[1]); orf.y = pkbf(v[2], v[3]);
    orf.z = pkbf(v[4], v[5]); orf.w = pkbf(v[6], v[7]);
    *(uint4*)(xt_lds + px * 128 + (((g + 8 + px) & 15) << 3)) = orf;
  }
  __syncthreads();

  // ---- coalesced xtb writer: 4 lanes cover one 128B row (x-half chunks 0..7) ----
  {
    const int px = t >> 2, j0 = (t & 3) << 1;   // row, chunks {j0, j0+1}
    const ushort* rowp = xt_lds + px * 128;
    uint4 c0 = *(const uint4*)(rowp + (((j0 + px) & 15) << 3));
    uint4 c1 = *(const uint4*)(rowp + (((j0 + 1 + px) & 15) << 3));
    ushort* dst = xtb + (((size_t)b << 14) + hw0 + px) * 64 + (j0 << 3);
    *(uint4*)dst       = c0;
    *(uint4*)(dst + 8) = c1;
  }

  // ---- GEMM: wave -> 16 oc, 4 ni x 4 ksteps MFMAs; A-fragments from global (L2) ----
  const int lane = t & 63, wv4 = t >> 6;
  const int ocl = lane & 15, kb = lane >> 4;
  const int ocr = (wv4 << 4) + ocl;
  f32x4 acc[4];
  #pragma unroll
  for (int ni = 0; ni < 4; ni++) acc[ni] = (f32x4){0.f, 0.f, 0.f, 0.f};
  #pragma unroll
  for (int s = 0; s < 4; s++) {
    const int gA = (s << 2) + kb;
    const float4* wr4 = (const float4*)(wcd + ocr * 128 + (gA << 3));
    float4 wa = wr4[0], wb2 = wr4[1];
    unsigned aw[4];
    aw[0] = pkbf(wa.x, wa.y);   aw[1] = pkbf(wa.z, wa.w);
    aw[2] = pkbf(wb2.x, wb2.y); aw[3] = pkbf(wb2.z, wb2.w);
    s16x8 af = *(const s16x8*)aw;
    #pragma unroll
    for (int ni = 0; ni < 4; ni++) {
      const int px = (ni << 4) + ocl;
      s16x8 bf8 = *(const s16x8*)(xt_lds + px * 128 + (((gA + px) & 15) << 3));
      acc[ni] = __builtin_amdgcn_mfma_f32_16x16x32_bf16(af, bf8, acc[ni], 0, 0, 0);
    }
  }
  __syncthreads();   // all MFMA reads of xt_lds done -> reuse as fusedt transpose buf

  // ---- fusedt epilogue: +bias, pack, transpose via LDS, coalesced store ----
  {
    ushort* ft = xt_lds;
    const float4 b4 = *(const float4*)&sb[(wv4 << 4) + (kb << 2)];
    #pragma unroll
    for (int ni = 0; ni < 4; ni++) {
      const int px = (ni << 4) + ocl;
      uint2 o;
      o.x = pkbf(acc[ni][0] + b4.x, acc[ni][1] + b4.y);
      o.y = pkbf(acc[ni][2] + b4.z, acc[ni][3] + b4.w);
      *(uint2*)(ft + px * 72 + (wv4 << 4) + (kb << 2)) = o;
    }
    __syncthreads();
    const int px = t >> 2, c0 = (t & 3) << 4;   // 4 lanes per 128B fusedt row
    uint4 f0 = *(const uint4*)(ft + px * 72 + c0);
    uint4 f1 = *(const uint4*)(ft + px * 72 + c0 + 8);
    ushort* dst = fusedt + (((size_t)(b << 14) + hw0 + px) << 6) + c0;
    *(uint4*)dst       = f0;
    *(uint4*)(dst + 8) = f1;
  }

  // ---- weight packing (former pack blocks), grid-strided over 262,144 threads ----
  const int gid = blockIdx.x * 256 + t;
  for (int i = gid; i < 368640; i += 262144) {
    int e = i & 7, lne = (i >> 3) & 63, mi = (i >> 9) & 3, ocq = (i >> 11) & 1;
    int hi = i >> 12;                 // 0..89
    int ks = hi % 18, og = hi / 18;
    int g = og * 128 + ocq * 64 + mi * 16 + (lne & 15);
    int ci = ((ks & 1) << 5) + ((lne >> 4) << 3) + e;
    int kk = ks >> 1;
    int col = ci * 9 + kk;
    float v = 0.f;
    if (g < 18)       v = wp[g * 576 + col];
    else if (g < 27)  v = wm[(g - 18) * 576 + col];
    else if (g >= 64) {
      int j = g - 64;
      int cc = (j & 63) * 9 + (j >> 6);
      v = wc[cc * 576 + col];
    }
    Wpk[i] = f2bf(v);
  }
  if (gid < 36864) {
    int e = gid & 7, lne = (gid >> 3) & 63, mi = (gid >> 9) & 3, ks = gid >> 11;  // 0..17
    int o = mi * 16 + (lne & 15);
    int p = (ks << 5) + ((lne >> 4) << 3) + e;
    int kk2 = p >> 6, c = p & 63;
    W2pk[gid] = f2bf(wconv[o * 576 + c * 9 + kk2]);
  }
  if (gid < 640) {
    float bv = 0.f;
    if (gid < 18)       bv = bp[gid];
    else if (gid < 27)  bv = bm[gid - 18];
    else if (gid >= 64) {
      int j = gid - 64;
      bv = bc[(j & 63) * 9 + (j >> 6)];
    }
    Bc[gid] = bv;
  }
}

// ---- K3: FULLY FUSED head-GEMM + sampler + final GEMM, 64-px tiles --------------------
// Round-8/11 structure (111-116 us, VGPR 64 -- the <=64-VGPR recompute-heavy regime is
// load-bearing). Round-14 delta: XCD-aware blockIdx swizzle (T1) ONLY. Default dispatch
// round-robins consecutive blocks across 8 XCDs, so neighbors sharing fusedt halo rows
// and xtb gather windows sit on DIFFERENT L2s (FETCH 40.8 MB vs 17.6 unique = 2.3x
// re-fetch). Bijective swizzle rowid=(bid&7)*128+(bid>>3) gives each XCD 128
// consecutive rowids (half an image): xtb/fusedt working set ~1.1 MB -> L2-resident,
// sampler gathers (between barriers, latency-exposed) drop to local-L2. 2 SALU, 0 VGPR.
// grid 1024; block 256 = 4 waves; 4 blocks/CU (LDS 40,448B).
__global__ __launch_bounds__(256) void k_all(
    const ushort* __restrict__ Wpk, const ushort* __restrict__ fusedt,
    const float* __restrict__ Bc, const ushort* __restrict__ xtb,
    const ushort* __restrict__ W2pk, float* __restrict__ out) {
  __shared__ __align__(16) ushort sF[3 * 66 * 64];    // 25,344 B
  __shared__ __align__(16) ushort colT[64 * 64];      //  8,192 B
  __shared__ float homT[64 * 27];                     //  6,912 B
  const int t = threadIdx.x;
  const int lane = t & 63, wv = t >> 6;
  const int bid0 = blockIdx.x;
  const int rowid = ((bid0 & 7) << 7) | (bid0 >> 3);  // XCD j -> rowids [j*128,(j+1)*128)
  const int b = rowid >> 8;
  const int rem = rowid & 255;
  const int h = rem >> 1, hf = rem & 1;
  const int w0 = hf << 6;
  const int hw0 = (h << 7) + w0;

  // stage fused rows h-1..h+1, w1 in [0,66) covering gw in [w0-1, w0+64]
  for (int idx = t; idx < 1584; idx += 256) {   // 198 pixels x 8 ci-chunks
    int p = idx >> 3, j = idx & 7;
    int row = p / 66, w1 = p - row * 66;
    int gh = h + row - 1, gw = w0 + w1 - 1;
    uint4 v = make_uint4(0u, 0u, 0u, 0u);
    if (gh >= 0 && gh < 128 && (unsigned)gw < 128u)
      v = *(const uint4*)(fusedt + ((size_t)((b << 14) + (gh << 7) + gw) << 6) + j * 8);
    int slot = (j + w1) & 7;
    *(uint4*)(sF + (p << 6) + slot * 8) = v;
  }
  __syncthreads();

  const int pxq = wv & 1, rowq = wv >> 1;
  const int nif = lane & 15, kb = lane >> 4, quad = lane >> 4;

  // ---- off/mod GEMM: permuted rows 0..31 (rowq==0 waves only) ----
  if (rowq == 0) {
    f32x4 acc[2][2];
    #pragma unroll
    for (int mi = 0; mi < 2; mi++)
      #pragma unroll
      for (int ni = 0; ni < 2; ni++) acc[mi][ni] = (f32x4){0.f, 0.f, 0.f, 0.f};
    __builtin_amdgcn_s_setprio(1);
    #pragma unroll 2
    for (int ks = 0; ks < 18; ks++) {
      const int kk = ks >> 1, half = ks & 1;
      const int dr = kk / 3, dc = kk - dr * 3;
      const ushort* wp8 = Wpk + ((size_t)(ks << 12)) + (lane << 3);  // og=0, ocq=0
      s16x8 af[2], bfr[2];
      #pragma unroll
      for (int mi = 0; mi < 2; mi++)
        af[mi] = *(const s16x8*)(wp8 + (mi << 9));
      const int gci = half * 4 + kb;
      #pragma unroll
      for (int ni = 0; ni < 2; ni++) {
        int r = (pxq << 5) + ni * 16 + nif;
        int w1 = r + dc;
        int slot = (gci + w1) & 7;
        bfr[ni] = *(const s16x8*)(sF + ((dr * 66 + w1) << 6) + slot * 8);
      }
      #pragma unroll
      for (int mi = 0; mi < 2; mi++)
        #pragma unroll
        for (int ni = 0; ni < 2; ni++)
          acc[mi][ni] = __builtin_amdgcn_mfma_f32_16x16x32_bf16(af[mi], bfr[ni], acc[mi][ni], 0, 0, 0);
    }
    __builtin_amdgcn_s_setprio(0);
    #pragma unroll
    for (int mi = 0; mi < 2; mi++) {
      #pragma unroll
      for (int ni = 0; ni < 2; ni++) {
        int px = (pxq << 5) + ni * 16 + nif;
        #pragma unroll
        for (int r = 0; r < 4; r++) {
          int g = mi * 16 + (quad << 2) + r;
          float v = acc[mi][ni][r] + Bc[g];
          if (g < 18)       homT[px * 27 + g] = v;
          else if (g < 27)  homT[px * 27 + g] = fast_sigmoid(v);
        }
      }
    }
  }

  // sampler per-pixel identity: 4 thr/px x 16 ch
  const int cq = t >> 6, pxl = t & 63, c0 = cq << 4;
  const int ww = w0 + pxl;
  const ushort* xb = xtb + ((size_t)b << 20);

  f32x4 aco[2][2];
  #pragma unroll
  for (int mi = 0; mi < 2; mi++)
    #pragma unroll
    for (int ni = 0; ni < 2; ni++) aco[mi][ni] = (f32x4){0.f, 0.f, 0.f, 0.f};

  #pragma unroll 1
  for (int k = 0; k < 9; k++) {
    // ---- col GEMM for this k: permuted rows 64+k*64 .. 128+k*64 ----
    const int q = 1 + k, og = q >> 1, ocq = q & 1;
    f32x4 acc[2][2];
    #pragma unroll
    for (int mi = 0; mi < 2; mi++)
      #pragma unroll
      for (int ni = 0; ni < 2; ni++) acc[mi][ni] = (f32x4){0.f, 0.f, 0.f, 0.f};
    __builtin_amdgcn_s_setprio(1);
    #pragma unroll 2
    for (int ks = 0; ks < 18; ks++) {
      const int kk = ks >> 1, half = ks & 1;
      const int dr = kk / 3, dc = kk - dr * 3;
      const ushort* wp8 = Wpk + ((size_t)((((og * 18 + ks) << 1) + ocq) << 11)) + (lane << 3);
      s16x8 af[2], bfr[2];
      #pragma unroll
      for (int mi = 0; mi < 2; mi++)
        af[mi] = *(const s16x8*)(wp8 + (((rowq << 1) + mi) << 9));
      const int gci = half * 4 + kb;
      #pragma unroll
      for (int ni = 0; ni < 2; ni++) {
        int r = (pxq << 5) + ni * 16 + nif;
        int w1 = r + dc;
        int slot = (gci + w1) & 7;
        bfr[ni] = *(const s16x8*)(sF + ((dr * 66 + w1) << 6) + slot * 8);
      }
      #pragma unroll
      for (int mi = 0; mi < 2; mi++)
        #pragma unroll
        for (int ni = 0; ni < 2; ni++)
          acc[mi][ni] = __builtin_amdgcn_mfma_f32_16x16x32_bf16(af[mi], bfr[ni], acc[mi][ni], 0, 0, 0);
    }
    __builtin_amdgcn_s_setprio(0);
    __syncthreads();   // prior k's finalMFMA reads of colT complete (k=0: homT visible)

    // epilogue: tanh -> colT (slot-rotated)
    #pragma unroll
    for (int mi = 0; mi < 2; mi++) {
      #pragma unroll
      for (int ni = 0; ni < 2; ni++) {
        int px = (pxq << 5) + ni * 16 + nif;
        int c = (rowq << 5) + mi * 16 + (quad << 2);
        float4 b4 = *(const float4*)(Bc + 64 + (k << 6) + c);
        ushort v4[4];
        v4[0] = f2bf(fast_tanh(acc[mi][ni][0] + b4.x));
        v4[1] = f2bf(fast_tanh(acc[mi][ni][1] + b4.y));
        v4[2] = f2bf(fast_tanh(acc[mi][ni][2] + b4.z));
        v4[3] = f2bf(fast_tanh(acc[mi][ni][3] + b4.w));
        int slot = ((c >> 3) + px) & 7;
        *(uint2*)(colT + (px << 6) + slot * 8 + (c & 7)) = *(uint2*)v4;
      }
    }
    __syncthreads();   // colT visible to sampler

    // ---- sampler: 16 channels of pixel pxl, in-place update of colT ----
    {
      float ox = homT[pxl * 27 + k];
      float oy = homT[pxl * 27 + 9 + k];
      float mk = homT[pxl * 27 + 18 + k];
      float px_ = (float)(h + k / 3) + ox;
      float py_ = (float)(ww + k % 3) + oy;
      float fx = floorf(px_), fy = floorf(py_);
      float qltx = fminf(fmaxf(fx, 0.f), 129.f);
      float qlty = fminf(fmaxf(fy, 0.f), 129.f);
      float qrbx = fminf(fmaxf(fx + 1.f, 0.f), 129.f);
      float qrby = fminf(fmaxf(fy + 1.f, 0.f), 129.f);
      float sx = fminf(fmaxf(px_, 0.f), 129.f);
      float sy = fminf(fmaxf(py_, 0.f), 129.f);
      float ax = 1.f + qltx - sx, bx = 1.f - qrbx + sx;
      float ay = 1.f + qlty - sy, by = 1.f - qrby + sy;
      int iltx = (int)qltx, ilty = (int)qlty, irbx = (int)qrbx, irby = (int)qrby;
      bool vltx = (iltx >= 1) && (iltx <= 128);
      bool vlty = (ilty >= 1) && (ilty <= 128);
      bool vrbx = (irbx >= 1) && (irbx <= 128);
      bool vrby = (irby >= 1) && (irby <= 128);
      float wl[4];
      int   ofs[4];
      wl[0] = (vltx && vlty) ? ax * ay : 0.f;
      wl[1] = (vrbx && vrby) ? bx * by : 0.f;
      wl[2] = (vltx && vrby) ? ax * by : 0.f;
      wl[3] = (vrbx && vlty) ? bx * ay : 0.f;
      ofs[0] = (vltx && vlty) ? ((iltx - 1) << 7) + (ilty - 1) : 0;
      ofs[1] = (vrbx && vrby) ? ((irbx - 1) << 7) + (irby - 1) : 0;
      ofs[2] = (vltx && vrby) ? ((iltx - 1) << 7) + (irby - 1) : 0;
      ofs[3] = (vrbx && vlty) ? ((irbx - 1) << 7) + (ilty - 1) : 0;

      float pos[16];
      #pragma unroll
      for (int j = 0; j < 16; j++) pos[j] = 0.f;
      #pragma unroll
      for (int corner = 0; corner < 4; corner++) {
        const ushort* p = xb + ((size_t)ofs[corner] << 6) + c0;
        float wgt = wl[corner];
        ushort tmp[16];
        *(uint4*)(tmp)     = *(const uint4*)(p);
        *(uint4*)(tmp + 8) = *(const uint4*)(p + 8);
        #pragma unroll
        for (int j = 0; j < 16; j++) pos[j] += wgt * bf2f(tmp[j]);
      }
      // read own col slots, update, write back (thread-exclusive -> no barrier)
      #pragma unroll
      for (int q2 = 0; q2 < 2; q2++) {
        int chunk = (cq << 1) + q2;
        int slot = (chunk + pxl) & 7;
        ushort* cp = colT + (pxl << 6) + slot * 8;
        ushort ct[8];
        *(uint4*)ct = *(const uint4*)cp;
        #pragma unroll
        for (int j = 0; j < 8; j++)
          ct[j] = f2bf((bf2f(ct[j]) + pos[q2 * 8 + j]) * mk);
        *(uint4*)cp = *(uint4*)ct;
      }
    }
    __syncthreads();   // updated colT visible to MFMA

    // ---- final-GEMM MFMA: 2 ks-steps over this k-tile ----
    __builtin_amdgcn_s_setprio(1);
    #pragma unroll
    for (int khalf = 0; khalf < 2; khalf++) {
      int ks2 = (k << 1) + khalf;
      s16x8 af[2], bfr[2];
      #pragma unroll
      for (int mi = 0; mi < 2; mi++)
        af[mi] = *(const s16x8*)(W2pk + ((((ks2 << 2) + (rowq << 1) + mi) << 6) + lane) * 8);
      const int g0 = (khalf << 2) + kb;
      #pragma unroll
      for (int ni = 0; ni < 2; ni++) {
        int r = (pxq << 5) + ni * 16 + nif;
        int slot = (g0 + r) & 7;
        bfr[ni] = *(const s16x8*)(colT + (r << 6) + slot * 8);
      }
      #pragma unroll
      for (int mi = 0; mi < 2; mi++)
        #pragma unroll
        for (int ni = 0; ni < 2; ni++)
          aco[mi][ni] = __builtin_amdgcn_mfma_f32_16x16x32_bf16(af[mi], bfr[ni], aco[mi][ni], 0, 0, 0);
    }
    __builtin_amdgcn_s_setprio(0);
  }

  // ---- store out ----
  #pragma unroll
  for (int mi = 0; mi < 2; mi++) {
    #pragma unroll
    for (int ni = 0; ni < 2; ni++) {
      int hwp = hw0 + (pxq << 5) + ni * 16 + nif;
      #pragma unroll
      for (int r = 0; r < 4; r++) {
        int o = (rowq << 5) + mi * 16 + (quad << 2) + r;
        out[(((size_t)b * 64 + o) << 14) + hwp] = aco[mi][ni][r];
      }
    }
  }
}

extern "C" void kernel_launch(void* const* d_in, const int* in_sizes, int n_in,
                              void* d_out, int out_size, void* d_ws, size_t ws_size,
                              hipStream_t stream) {
  const float* x     = (const float*)d_in[0];
  const float* ref   = (const float*)d_in[1];
  const float* wcd   = (const float*)d_in[2];
  const float* bcd   = (const float*)d_in[3];
  const float* wp    = (const float*)d_in[4];
  const float* bp    = (const float*)d_in[5];
  const float* wm    = (const float*)d_in[6];
  const float* bm    = (const float*)d_in[7];
  const float* wc    = (const float*)d_in[8];
  const float* bc    = (const float*)d_in[9];
  const float* wconv = (const float*)d_in[10];
  float* out = (float*)d_out;

  char* w8 = (char*)d_ws;
  ushort* Wpk     = (ushort*)(w8 + 0);           //    737,280 B
  float*  Bc      = (float*)(w8 + 737280);       //      2,560 B
  ushort* W2pk    = (ushort*)(w8 + 739840);      //     73,728 B
  ushort* fusedt  = (ushort*)(w8 + 813568);      //  8,388,608 B (pixel-major)
  ushort* xtb     = (ushort*)(w8 + 9202176);     //  8,388,608 B -> total 17,590,784 B

  k_fused <<<1024, 256, 0, stream>>>(x, ref, wcd, bcd, wp, bp, wm, bm, wc, bc, wconv,
                                     fusedt, xtb, Wpk, Bc, W2pk);
  k_all   <<<1024, 256, 0, stream>>>(Wpk, fusedt, Bc, xtb, W2pk, out);
}